// Round 1
// baseline (7928.189 us; speedup 1.0000x reference)
//
#include <hip/hip_runtime.h>
#include <math.h>

#define RTOT 19200          // 4*4800 rows
#define CDIM 256
#define SLEN 4800
#define NBATCH 4
#define NHEAD 8
#define HDIM 32
#define SEG 20              // segments for KV reduction
#define SCHUNK (SLEN/SEG)   // 240

// ---------------- activation ----------------
template<int ACT> __device__ __forceinline__ float actf(float v) {
    if (ACT == 1) return v > 0.0f ? v + 1.0f : __expf(v);   // elu(x)+1
    if (ACT == 2) return v > 0.0f ? v : 0.0f;               // relu
    return v;
}

// ---------------- GEMM: C[M,N] = act(A[M,K] @ B[K,N]) ----------------
// CONCAT: A is concat(A(256 cols), A2(256 cols)) along K (both lda=256)
template<int ACT, bool CONCAT>
__global__ __launch_bounds__(256) void gemm_k(
    const float* __restrict__ A, const float* __restrict__ A2,
    const float* __restrict__ B, float* __restrict__ C,
    int M, int N, int K)
{
    __shared__ float As[16][68];
    __shared__ float Bs[16][68];
    const int t = threadIdx.x;
    const int bm = blockIdx.y * 64;
    const int bn = blockIdx.x * 64;
    const int tx = t & 15, ty = t >> 4;
    const int arow = t >> 2, acol = (t & 3) * 4;
    const int brow = t >> 4, bcol = (t & 15) * 4;
    float acc[4][4] = {};

    for (int k0 = 0; k0 < K; k0 += 16) {
        float4 av;
        if (CONCAT) {
            int gk = k0 + acol;
            const float* asrc = A; int col = gk;
            if (gk >= 256) { asrc = A2; col = gk - 256; }
            av = *(const float4*)&asrc[(size_t)(bm + arow) * 256 + col];
        } else {
            av = *(const float4*)&A[(size_t)(bm + arow) * K + k0 + acol];
        }
        As[acol + 0][arow] = av.x;
        As[acol + 1][arow] = av.y;
        As[acol + 2][arow] = av.z;
        As[acol + 3][arow] = av.w;

        float4 bv = *(const float4*)&B[(size_t)(k0 + brow) * N + bn + bcol];
        *(float4*)&Bs[brow][bcol] = bv;
        __syncthreads();

        #pragma unroll
        for (int k = 0; k < 16; ++k) {
            float4 a = *(const float4*)&As[k][ty * 4];
            float4 b = *(const float4*)&Bs[k][tx * 4];
            acc[0][0] += a.x * b.x; acc[0][1] += a.x * b.y; acc[0][2] += a.x * b.z; acc[0][3] += a.x * b.w;
            acc[1][0] += a.y * b.x; acc[1][1] += a.y * b.y; acc[1][2] += a.y * b.z; acc[1][3] += a.y * b.w;
            acc[2][0] += a.z * b.x; acc[2][1] += a.z * b.y; acc[2][2] += a.z * b.z; acc[2][3] += a.z * b.w;
            acc[3][0] += a.w * b.x; acc[3][1] += a.w * b.y; acc[3][2] += a.w * b.z; acc[3][3] += a.w * b.w;
        }
        __syncthreads();
    }

    #pragma unroll
    for (int i = 0; i < 4; ++i) {
        float4 o;
        o.x = actf<ACT>(acc[i][0]);
        o.y = actf<ACT>(acc[i][1]);
        o.z = actf<ACT>(acc[i][2]);
        o.w = actf<ACT>(acc[i][3]);
        *(float4*)&C[(size_t)(bm + ty * 4 + i) * N + bn + tx * 4] = o;
    }
}

// ---------------- KV partial reduction ----------------
// KVp[(nh*SEG+seg)*1024 + d*32+v] = sum_{s in seg} K[n,s,h,d]*V[n,s,h,v]
// Ksp[(nh*SEG+seg)*32 + d]        = sum_{s in seg} K[n,s,h,d]
__global__ __launch_bounds__(256) void kv_part_k(
    const float* __restrict__ Kb, const float* __restrict__ Vb,
    float* __restrict__ KVp, float* __restrict__ Ksp)
{
    const int blk = blockIdx.x;
    const int seg = blk % SEG;
    const int h = (blk / SEG) % NHEAD;
    const int n = blk / (SEG * NHEAD);
    const int s0 = seg * SCHUNK;
    __shared__ float Ks[8][32];
    __shared__ float Vs[8][32];
    const int t = threadIdx.x;
    const int v0 = (t * 4) & 31;
    const int d = (t * 4) >> 5;
    float acc0 = 0, acc1 = 0, acc2 = 0, acc3 = 0;
    float ksum = 0;
    for (int c = 0; c < SCHUNK; c += 8) {
        const int ss = t >> 5, col = t & 31;
        const size_t row = (size_t)(n * SLEN + s0 + c + ss);
        const size_t off = row * CDIM + h * HDIM + col;
        Ks[ss][col] = Kb[off];
        Vs[ss][col] = Vb[off];
        __syncthreads();
        #pragma unroll
        for (int q = 0; q < 8; ++q) {
            float kd = Ks[q][d];
            acc0 += kd * Vs[q][v0 + 0];
            acc1 += kd * Vs[q][v0 + 1];
            acc2 += kd * Vs[q][v0 + 2];
            acc3 += kd * Vs[q][v0 + 3];
        }
        if (t < 32) {
            #pragma unroll
            for (int q = 0; q < 8; ++q) ksum += Ks[q][t];
        }
        __syncthreads();
    }
    float* kvp = KVp + ((size_t)((n * NHEAD + h) * SEG + seg)) * 1024;
    kvp[t * 4 + 0] = acc0;
    kvp[t * 4 + 1] = acc1;
    kvp[t * 4 + 2] = acc2;
    kvp[t * 4 + 3] = acc3;
    if (t < 32) Ksp[((size_t)((n * NHEAD + h) * SEG + seg)) * 32 + t] = ksum;
}

__global__ __launch_bounds__(256) void kv_reduce_k(
    const float* __restrict__ KVp, const float* __restrict__ Ksp,
    float* __restrict__ KV, float* __restrict__ Ksum)
{
    const int nh = blockIdx.x;
    const int t = threadIdx.x;
    float a0 = 0, a1 = 0, a2 = 0, a3 = 0;
    for (int seg = 0; seg < SEG; ++seg) {
        const float* p = KVp + ((size_t)(nh * SEG + seg)) * 1024;
        a0 += p[t * 4 + 0];
        a1 += p[t * 4 + 1];
        a2 += p[t * 4 + 2];
        a3 += p[t * 4 + 3];
    }
    KV[(size_t)nh * 1024 + t * 4 + 0] = a0;
    KV[(size_t)nh * 1024 + t * 4 + 1] = a1;
    KV[(size_t)nh * 1024 + t * 4 + 2] = a2;
    KV[(size_t)nh * 1024 + t * 4 + 3] = a3;
    if (t < 32) {
        float s = 0;
        for (int seg = 0; seg < SEG; ++seg) s += Ksp[(size_t)(nh * SEG + seg) * 32 + t];
        Ksum[nh * 32 + t] = s;
    }
}

// ---------------- attention message: msg = (Q @ KV) / (Q . Ksum + eps) ----------------
__global__ __launch_bounds__(256) void attn_k(
    const float* __restrict__ Q, const float* __restrict__ KV,
    const float* __restrict__ Ksum, float* __restrict__ msg)
{
    const int blk = blockIdx.x;
    const int n = blk / (SLEN / 16);
    const int r0 = (blk % (SLEN / 16)) * 16;
    __shared__ float KVs[NHEAD * 1024];
    __shared__ float Kss[NHEAD * 32];
    __shared__ float Qs[256];
    const int t = threadIdx.x;
    for (int i = t; i < NHEAD * 1024; i += 256) KVs[i] = KV[(size_t)n * NHEAD * 1024 + i];
    if (t < NHEAD * 32) Kss[t] = Ksum[n * NHEAD * 32 + t];
    __syncthreads();
    const int h = t >> 5, v = t & 31;
    for (int r = 0; r < 16; ++r) {
        const size_t row = (size_t)(n * SLEN + r0 + r);
        Qs[t] = Q[row * CDIM + t];
        __syncthreads();
        float z = 0, m = 0;
        #pragma unroll
        for (int d = 0; d < HDIM; ++d) {
            float qd = Qs[h * 32 + d];
            z += qd * Kss[h * 32 + d];
            m += qd * KVs[(h * 32 + d) * 32 + v];
        }
        msg[row * CDIM + t] = m / (z + 1e-6f);
        __syncthreads();
    }
}

// ---------------- LayerNorm (optionally + residual) ----------------
template<bool RES>
__global__ __launch_bounds__(256) void ln_k(
    const float* __restrict__ X, const float* __restrict__ resid,
    const float* __restrict__ g, const float* __restrict__ b,
    float* __restrict__ out)
{
    const int lane = threadIdx.x & 63;
    const size_t row = (size_t)blockIdx.x * 4 + (threadIdx.x >> 6);
    const float* xr = X + row * CDIM;
    float4 x = *(const float4*)&xr[lane * 4];
    float s = x.x + x.y + x.z + x.w;
    #pragma unroll
    for (int off = 32; off > 0; off >>= 1) s += __shfl_xor(s, off);
    const float mu = s * (1.0f / 256.0f);
    float cx = x.x - mu, cy = x.y - mu, cz = x.z - mu, cw = x.w - mu;
    float sq = cx * cx + cy * cy + cz * cz + cw * cw;
    #pragma unroll
    for (int off = 32; off > 0; off >>= 1) sq += __shfl_xor(sq, off);
    const float inv = rsqrtf(sq * (1.0f / 256.0f) + 1e-5f);
    float4 gv = *(const float4*)&g[lane * 4];
    float4 bv = *(const float4*)&b[lane * 4];
    float4 o;
    o.x = cx * inv * gv.x + bv.x;
    o.y = cy * inv * gv.y + bv.y;
    o.z = cz * inv * gv.z + bv.z;
    o.w = cw * inv * gv.w + bv.w;
    if (RES) {
        float4 rv = *(const float4*)&resid[row * CDIM + lane * 4];
        o.x += rv.x; o.y += rv.y; o.z += rv.z; o.w += rv.w;
    }
    *(float4*)&out[row * CDIM + lane * 4] = o;
}

__global__ __launch_bounds__(256) void copy_k(const float* __restrict__ src, float* __restrict__ dst) {
    const size_t i = ((size_t)blockIdx.x * 256 + threadIdx.x) * 4;
    *(float4*)&dst[i] = *(const float4*)&src[i];
}

// ---------------- host-side orchestration ----------------
struct Ws {
    float *Q, *Kb, *Vb, *h1, *tmp0, *KVp, *Ksp, *KV, *Ksum;
};

static void encoder_layer(const float* x, const float* src, float* dest,
                          const float* Wq, const float* Wk, const float* Wv,
                          const float* Wm, const float* W1, const float* W2,
                          const float* g1, const float* b1,
                          const float* g2, const float* b2,
                          const Ws& w, hipStream_t stream)
{
    const dim3 blk(256);
    const dim3 g256(256 / 64, RTOT / 64);   // N=256 GEMMs
    const dim3 g512(512 / 64, RTOT / 64);   // N=512 GEMM
    // Q = elu(x@Wq)+1 ; K = elu(src@Wk)+1 ; V = src@Wv
    gemm_k<1, false><<<g256, blk, 0, stream>>>(x,   nullptr, Wq, w.Q,  RTOT, 256, 256);
    gemm_k<1, false><<<g256, blk, 0, stream>>>(src, nullptr, Wk, w.Kb, RTOT, 256, 256);
    gemm_k<0, false><<<g256, blk, 0, stream>>>(src, nullptr, Wv, w.Vb, RTOT, 256, 256);
    // KV = K^T V (per n,h), Ksum = sum_s K
    kv_part_k<<<dim3(NBATCH * NHEAD * SEG), blk, 0, stream>>>(w.Kb, w.Vb, w.KVp, w.Ksp);
    kv_reduce_k<<<dim3(NBATCH * NHEAD), blk, 0, stream>>>(w.KVp, w.Ksp, w.KV, w.Ksum);
    // msg = (Q@KV) * 1/(Q.Ksum+eps)   -> Kb (K is dead)
    attn_k<<<dim3(NBATCH * (SLEN / 16)), blk, 0, stream>>>(w.Q, w.KV, w.Ksum, w.Kb);
    // msgW = msg @ Wm -> Vb (V is dead)
    gemm_k<0, false><<<g256, blk, 0, stream>>>(w.Kb, nullptr, Wm, w.Vb, RTOT, 256, 256);
    // msgln = LN(msgW) -> Q (Q is dead)
    ln_k<false><<<dim3(RTOT / 4), blk, 0, stream>>>(w.Vb, nullptr, g1, b1, w.Q);
    // h1 = relu(concat(x, msgln) @ W1)
    gemm_k<2, true><<<g512, blk, 0, stream>>>(x, w.Q, W1, w.h1, RTOT, 512, 512);
    // h2 = h1 @ W2 -> Kb
    gemm_k<0, false><<<g256, blk, 0, stream>>>(w.h1, nullptr, W2, w.Kb, RTOT, 256, 512);
    // dest = x + LN(h2)
    ln_k<true><<<dim3(RTOT / 4), blk, 0, stream>>>(w.Kb, x, g2, b2, dest);
}

extern "C" void kernel_launch(void* const* d_in, const int* in_sizes, int n_in,
                              void* d_out, int out_size, void* d_ws, size_t ws_size,
                              hipStream_t stream) {
    (void)in_sizes; (void)n_in; (void)out_size; (void)ws_size;
    const float* f0in = (const float*)d_in[0];
    const float* f1in = (const float*)d_in[1];
    const float* WqA = (const float*)d_in[2];
    const float* WkA = (const float*)d_in[3];
    const float* WvA = (const float*)d_in[4];
    const float* WmA = (const float*)d_in[5];
    const float* W1A = (const float*)d_in[6];
    const float* W2A = (const float*)d_in[7];
    const float* g1A = (const float*)d_in[8];
    const float* b1A = (const float*)d_in[9];
    const float* g2A = (const float*)d_in[10];
    const float* b2A = (const float*)d_in[11];

    float* out0 = (float*)d_out;
    float* out1 = out0 + (size_t)RTOT * CDIM;

    const size_t RC = (size_t)RTOT * CDIM;
    float* ws = (float*)d_ws;
    Ws w;
    w.Q    = ws;                   // RC
    w.Kb   = w.Q + RC;             // RC
    w.Vb   = w.Kb + RC;            // RC
    w.h1   = w.Vb + RC;            // R*512
    w.tmp0 = w.h1 + (size_t)RTOT * 512;  // RC
    w.KVp  = w.tmp0 + RC;          // 32*SEG*1024
    w.Ksp  = w.KVp + 32 * SEG * 1024;    // 32*SEG*32
    w.KV   = w.Ksp + 32 * SEG * 32;      // 32*1024
    w.Ksum = w.KV + 32 * 1024;           // 32*32

    const dim3 blk(256);
    const dim3 cg(RC / 1024);
    copy_k<<<cg, blk, 0, stream>>>(f0in, out0);
    copy_k<<<cg, blk, 0, stream>>>(f1in, out1);

    for (int l = 0; l < 8; ++l) {
        const float* Wq = WqA + (size_t)l * 256 * 256;
        const float* Wk = WkA + (size_t)l * 256 * 256;
        const float* Wv = WvA + (size_t)l * 256 * 256;
        const float* Wm = WmA + (size_t)l * 256 * 256;
        const float* W1 = W1A + (size_t)l * 512 * 512;
        const float* W2 = W2A + (size_t)l * 512 * 256;
        const float* g1 = g1A + l * 256;
        const float* b1 = b1A + l * 256;
        const float* g2 = g2A + l * 256;
        const float* b2 = b2A + l * 256;
        if ((l & 1) == 0) {
            // self: feat0 = layer(feat0, feat0); feat1 = layer(feat1, feat1)
            encoder_layer(out0, out0, out0, Wq, Wk, Wv, Wm, W1, W2, g1, b1, g2, b2, w, stream);
            encoder_layer(out1, out1, out1, Wq, Wk, Wv, Wm, W1, W2, g1, b1, g2, b2, w, stream);
        } else {
            // cross: new0 = layer(feat0, feat1); feat1 = layer(feat1, feat0_old); feat0 = new0
            encoder_layer(out0, out1, w.tmp0, Wq, Wk, Wv, Wm, W1, W2, g1, b1, g2, b2, w, stream);
            encoder_layer(out1, out0, out1, Wq, Wk, Wv, Wm, W1, W2, g1, b1, g2, b2, w, stream);
            copy_k<<<cg, blk, 0, stream>>>(w.tmp0, out0);
        }
    }
}

// Round 2
// 2711.560 us; speedup vs baseline: 2.9238x; 2.9238x over previous
//
#include <hip/hip_runtime.h>
#include <math.h>

#define RTOT 19200          // 4*4800 rows
#define CDIM 256
#define SLEN 4800
#define NBATCH 4
#define NHEAD 8
#define HDIM 32
#define SEG 20
#define SCHUNK (SLEN/SEG)   // 240

typedef __attribute__((ext_vector_type(8))) short short8v;
typedef __attribute__((ext_vector_type(4))) float f32x4;

__device__ __forceinline__ ushort f2b(float f) {           // fp32 -> bf16 RNE
    unsigned u = __float_as_uint(f);
    unsigned r = (u + 0x7FFFu + ((u >> 16) & 1u)) >> 16;
    return (ushort)r;
}

template<int ACT> __device__ __forceinline__ float actf(float v) {
    if (ACT == 1) return v > 0.0f ? v + 1.0f : __expf(v);   // elu(x)+1
    if (ACT == 2) return v > 0.0f ? v : 0.0f;               // relu
    return v;
}

__device__ __forceinline__ void gload16(const void* g, void* l) {
    __builtin_amdgcn_global_load_lds((const __attribute__((address_space(1))) void*)g,
                                     (__attribute__((address_space(3))) void*)l, 16, 0, 0);
}

// ---------------- bf16 MFMA GEMM ----------------
// C[M,N] = act(A[M,K] @ B[K,N]); A bf16 row-major (lda), Bt bf16 [N][K] (pre-transposed).
// CONCAT: A = concat(A(256 cols), A2(256 cols)) along K, both lda=256.
// OUTB: write bf16 output, else fp32.
template<int ACT, bool CONCAT, bool OUTB>
__global__ __launch_bounds__(256) void gemm_bf16(
    const ushort* __restrict__ A, const ushort* __restrict__ A2, int lda,
    const ushort* __restrict__ Bt,
    float* __restrict__ Cf, ushort* __restrict__ Cb,
    int N, int K)
{
    __shared__ __align__(16) ushort As[128 * 32];
    __shared__ __align__(16) ushort Bs[128 * 32];
    const int t = threadIdx.x;
    const int wave = t >> 6, lane = t & 63;
    const int bm = blockIdx.y * 128, bn = blockIdx.x * 128;
    const int wr = wave >> 1, wc = wave & 1;
    const int lr = lane & 15, lk = (lane >> 4) * 8;

    // staging: thread t loads 8 bf16 (16B); 4 threads per row; 2 issues cover 128 rows.
    // group index XOR-swizzled by (row&3) on source so linear LDS + swizzled read match.
    const int srow = t >> 2;
    const int sgrp = ((t & 3) * 8) ^ ((srow & 3) * 8);
    const ushort* bAr = A + (size_t)(bm + srow) * lda + sgrp;
    const ushort* bA2r = CONCAT ? (A2 + (size_t)(bm + srow) * lda + sgrp) : (const ushort*)0;
    const ushort* bBr = Bt + (size_t)(bn + srow) * K + sgrp;
    char* ldsA = (char*)As + wave * 1024;
    char* ldsB = (char*)Bs + wave * 1024;
    const size_t a64 = (size_t)64 * lda;
    const size_t b64 = (size_t)64 * K;

    const f32x4 z4 = {0.f, 0.f, 0.f, 0.f};
    f32x4 acc[4][4];
    #pragma unroll
    for (int m = 0; m < 4; ++m)
        #pragma unroll
        for (int n = 0; n < 4; ++n) acc[m][n] = z4;

    for (int k0 = 0; k0 < K; k0 += 32) {
        const ushort* ga;
        if (CONCAT) ga = (k0 < 256) ? (bAr + k0) : (bA2r + (k0 - 256));
        else        ga = bAr + k0;
        gload16(ga, ldsA);
        gload16(ga + a64, ldsA + 4096);
        gload16(bBr + k0, ldsB);
        gload16(bBr + k0 + b64, ldsB + 4096);
        __syncthreads();

        short8v af[4], bfr[4];
        #pragma unroll
        for (int m = 0; m < 4; ++m) {
            const int r = wr * 64 + m * 16 + lr;
            af[m] = *(const short8v*)&As[r * 32 + (lk ^ ((r & 3) * 8))];
        }
        #pragma unroll
        for (int n = 0; n < 4; ++n) {
            const int r = wc * 64 + n * 16 + lr;
            bfr[n] = *(const short8v*)&Bs[r * 32 + (lk ^ ((r & 3) * 8))];
        }
        #pragma unroll
        for (int m = 0; m < 4; ++m)
            #pragma unroll
            for (int n = 0; n < 4; ++n)
                acc[m][n] = __builtin_amdgcn_mfma_f32_16x16x32_bf16(af[m], bfr[n], acc[m][n], 0, 0, 0);
        __syncthreads();
    }

    // C/D layout: col = lane&15, row = (lane>>4)*4 + j
    const int orow = bm + wr * 64 + (lane >> 4) * 4;
    const int ocol = bn + wc * 64 + lr;
    #pragma unroll
    for (int m = 0; m < 4; ++m)
        #pragma unroll
        for (int n = 0; n < 4; ++n)
            #pragma unroll
            for (int j = 0; j < 4; ++j) {
                const float v = actf<ACT>(acc[m][n][j]);
                const size_t idx = (size_t)(orow + m * 16 + j) * N + (ocol + n * 16);
                if (OUTB) Cb[idx] = f2b(v);
                else      Cf[idx] = v;
            }
}

// ---------------- weight transpose + bf16 convert: src [L][R][C] -> dst [L][C][R] ----------------
__global__ __launch_bounds__(256) void wconv_t(
    const float* __restrict__ src, ushort* __restrict__ dst, int R, int C)
{
    __shared__ float tile[32][33];
    const int l = blockIdx.z;
    const int r0 = blockIdx.y * 32, c0 = blockIdx.x * 32;
    const int tx = threadIdx.x & 31, ty = threadIdx.x >> 5;
    const float* s = src + (size_t)l * R * C;
    ushort* d = dst + (size_t)l * R * C;
    for (int i = ty; i < 32; i += 8) tile[i][tx] = s[(size_t)(r0 + i) * C + c0 + tx];
    __syncthreads();
    for (int i = ty; i < 32; i += 8) d[(size_t)(c0 + i) * R + r0 + tx] = f2b(tile[tx][i]);
}

// ---------------- KV partial reduction (fp32) ----------------
__global__ __launch_bounds__(256) void kv_part_k(
    const float* __restrict__ Kb, const float* __restrict__ Vb,
    float* __restrict__ KVp, float* __restrict__ Ksp)
{
    const int blk = blockIdx.x;
    const int seg = blk % SEG;
    const int h = (blk / SEG) % NHEAD;
    const int n = blk / (SEG * NHEAD);
    const int s0 = seg * SCHUNK;
    __shared__ float Ks[8][32];
    __shared__ float Vs[8][32];
    const int t = threadIdx.x;
    const int v0 = (t * 4) & 31;
    const int d = (t * 4) >> 5;
    float acc0 = 0, acc1 = 0, acc2 = 0, acc3 = 0;
    float ksum = 0;
    for (int c = 0; c < SCHUNK; c += 8) {
        const int ss = t >> 5, col = t & 31;
        const size_t row = (size_t)(n * SLEN + s0 + c + ss);
        const size_t off = row * CDIM + h * HDIM + col;
        Ks[ss][col] = Kb[off];
        Vs[ss][col] = Vb[off];
        __syncthreads();
        #pragma unroll
        for (int q = 0; q < 8; ++q) {
            float kd = Ks[q][d];
            acc0 += kd * Vs[q][v0 + 0];
            acc1 += kd * Vs[q][v0 + 1];
            acc2 += kd * Vs[q][v0 + 2];
            acc3 += kd * Vs[q][v0 + 3];
        }
        if (t < 32) {
            #pragma unroll
            for (int q = 0; q < 8; ++q) ksum += Ks[q][t];
        }
        __syncthreads();
    }
    float* kvp = KVp + ((size_t)((n * NHEAD + h) * SEG + seg)) * 1024;
    kvp[t * 4 + 0] = acc0;
    kvp[t * 4 + 1] = acc1;
    kvp[t * 4 + 2] = acc2;
    kvp[t * 4 + 3] = acc3;
    if (t < 32) Ksp[((size_t)((n * NHEAD + h) * SEG + seg)) * 32 + t] = ksum;
}

__global__ __launch_bounds__(256) void kv_reduce_k(
    const float* __restrict__ KVp, const float* __restrict__ Ksp,
    float* __restrict__ KV, float* __restrict__ Ksum)
{
    const int nh = blockIdx.x;
    const int t = threadIdx.x;
    float a0 = 0, a1 = 0, a2 = 0, a3 = 0;
    for (int seg = 0; seg < SEG; ++seg) {
        const float* p = KVp + ((size_t)(nh * SEG + seg)) * 1024;
        a0 += p[t * 4 + 0];
        a1 += p[t * 4 + 1];
        a2 += p[t * 4 + 2];
        a3 += p[t * 4 + 3];
    }
    KV[(size_t)nh * 1024 + t * 4 + 0] = a0;
    KV[(size_t)nh * 1024 + t * 4 + 1] = a1;
    KV[(size_t)nh * 1024 + t * 4 + 2] = a2;
    KV[(size_t)nh * 1024 + t * 4 + 3] = a3;
    if (t < 32) {
        float s = 0;
        for (int seg = 0; seg < SEG; ++seg) s += Ksp[(size_t)(nh * SEG + seg) * 32 + t];
        Ksum[nh * 32 + t] = s;
    }
}

// ---------------- attention message: msg = (Q @ KV) / (Q . Ksum + eps), bf16 out ----------------
__global__ __launch_bounds__(256) void attn_k(
    const float* __restrict__ Q, const float* __restrict__ KV,
    const float* __restrict__ Ksum, ushort* __restrict__ msg)
{
    const int blk = blockIdx.x;
    const int n = blk / (SLEN / 16);
    const int r0 = (blk % (SLEN / 16)) * 16;
    __shared__ float KVs[NHEAD * 1024];
    __shared__ float Kss[NHEAD * 32];
    __shared__ float Qs[256];
    const int t = threadIdx.x;
    for (int i = t; i < NHEAD * 1024; i += 256) KVs[i] = KV[(size_t)n * NHEAD * 1024 + i];
    if (t < NHEAD * 32) Kss[t] = Ksum[n * NHEAD * 32 + t];
    __syncthreads();
    const int h = t >> 5, v = t & 31;
    for (int r = 0; r < 16; ++r) {
        const size_t row = (size_t)(n * SLEN + r0 + r);
        Qs[t] = Q[row * CDIM + t];
        __syncthreads();
        float z = 0, m = 0;
        #pragma unroll
        for (int d = 0; d < HDIM; ++d) {
            float qd = Qs[h * 32 + d];
            z += qd * Kss[h * 32 + d];
            m += qd * KVs[(h * 32 + d) * 32 + v];
        }
        msg[row * CDIM + t] = f2b(m / (z + 1e-6f));
        __syncthreads();
    }
}

// ---------------- LayerNorm (optional residual, fp32/bf16 outs) ----------------
template<bool RES, bool OF, bool OB>
__global__ __launch_bounds__(256) void ln_k(
    const float* __restrict__ X, const float* __restrict__ resid,
    const float* __restrict__ g, const float* __restrict__ b,
    float* __restrict__ outf, ushort* __restrict__ outb)
{
    const int lane = threadIdx.x & 63;
    const size_t row = (size_t)blockIdx.x * 4 + (threadIdx.x >> 6);
    const float* xr = X + row * CDIM;
    float4 x = *(const float4*)&xr[lane * 4];
    float s = x.x + x.y + x.z + x.w;
    #pragma unroll
    for (int off = 32; off > 0; off >>= 1) s += __shfl_xor(s, off);
    const float mu = s * (1.0f / 256.0f);
    float cx = x.x - mu, cy = x.y - mu, cz = x.z - mu, cw = x.w - mu;
    float sq = cx * cx + cy * cy + cz * cz + cw * cw;
    #pragma unroll
    for (int off = 32; off > 0; off >>= 1) sq += __shfl_xor(sq, off);
    const float inv = rsqrtf(sq * (1.0f / 256.0f) + 1e-5f);
    float4 gv = *(const float4*)&g[lane * 4];
    float4 bv = *(const float4*)&b[lane * 4];
    float4 o;
    o.x = cx * inv * gv.x + bv.x;
    o.y = cy * inv * gv.y + bv.y;
    o.z = cz * inv * gv.z + bv.z;
    o.w = cw * inv * gv.w + bv.w;
    if (RES) {
        float4 rv = *(const float4*)&resid[row * CDIM + lane * 4];
        o.x += rv.x; o.y += rv.y; o.z += rv.z; o.w += rv.w;
    }
    if (OF) *(float4*)&outf[row * CDIM + lane * 4] = o;
    if (OB) {
        ushort4 ob = make_ushort4(f2b(o.x), f2b(o.y), f2b(o.z), f2b(o.w));
        *(ushort4*)&outb[row * CDIM + lane * 4] = ob;
    }
}

// copy fp32 -> fp32 + bf16 mirror
__global__ __launch_bounds__(256) void copy2_k(
    const float* __restrict__ src, float* __restrict__ dstf, ushort* __restrict__ dstb)
{
    const size_t i = ((size_t)blockIdx.x * 256 + threadIdx.x) * 4;
    float4 v = *(const float4*)&src[i];
    *(float4*)&dstf[i] = v;
    ushort4 ob = make_ushort4(f2b(v.x), f2b(v.y), f2b(v.z), f2b(v.w));
    *(ushort4*)&dstb[i] = ob;
}

// ---------------- host-side orchestration ----------------
struct Ws {
    float *Q, *Kf, *Vf, *tmp0, *KVp, *Ksp, *KV, *Ksum;
    ushort *msgb, *mlnb, *h1b, *xb0, *xb1;
    ushort *WqT, *WkT, *WvT, *WmT, *W1T, *W2T;
};

static void encoder_layer(const float* x, const ushort* xb, const ushort* srcb,
                          float* destf, ushort* destb,
                          const ushort* WqT, const ushort* WkT, const ushort* WvT,
                          const ushort* WmT, const ushort* W1T, const ushort* W2T,
                          const float* g1, const float* b1,
                          const float* g2, const float* b2,
                          const Ws& w, hipStream_t stream)
{
    const dim3 blk(256);
    const dim3 g2d(256 / 128, RTOT / 128);   // (2,150)
    const dim3 g4d(512 / 128, RTOT / 128);   // (4,150)
    // Q = elu(xb@Wq)+1 ; K = elu(srcb@Wk)+1 ; V = srcb@Wv   (fp32 outs)
    gemm_bf16<1, false, false><<<g2d, blk, 0, stream>>>(xb,   nullptr, 256, WqT, w.Q,  nullptr, 256, 256);
    gemm_bf16<1, false, false><<<g2d, blk, 0, stream>>>(srcb, nullptr, 256, WkT, w.Kf, nullptr, 256, 256);
    gemm_bf16<0, false, false><<<g2d, blk, 0, stream>>>(srcb, nullptr, 256, WvT, w.Vf, nullptr, 256, 256);
    // KV = K^T V, Ksum = sum_s K
    kv_part_k<<<dim3(NBATCH * NHEAD * SEG), blk, 0, stream>>>(w.Kf, w.Vf, w.KVp, w.Ksp);
    kv_reduce_k<<<dim3(NBATCH * NHEAD), blk, 0, stream>>>(w.KVp, w.Ksp, w.KV, w.Ksum);
    // msg (bf16)
    attn_k<<<dim3(NBATCH * (SLEN / 16)), blk, 0, stream>>>(w.Q, w.KV, w.Ksum, w.msgb);
    // msgW = msg @ Wm -> Kf (fp32, Kf dead)
    gemm_bf16<0, false, false><<<g2d, blk, 0, stream>>>(w.msgb, nullptr, 256, WmT, w.Kf, nullptr, 256, 256);
    // msgln = LN(msgW) -> mlnb (bf16 only)
    ln_k<false, false, true><<<dim3(RTOT / 4), blk, 0, stream>>>(w.Kf, nullptr, g1, b1, nullptr, w.mlnb);
    // h1 = relu(concat(xb, mlnb) @ W1) -> h1b (bf16 only)
    gemm_bf16<2, true, true><<<g4d, blk, 0, stream>>>(xb, w.mlnb, 256, W1T, nullptr, w.h1b, 512, 512);
    // h2 = h1 @ W2 -> Vf (fp32, Vf dead)
    gemm_bf16<0, false, false><<<g2d, blk, 0, stream>>>(w.h1b, nullptr, 512, W2T, w.Vf, nullptr, 256, 512);
    // dest = x + LN(h2)
    ln_k<true, true, true><<<dim3(RTOT / 4), blk, 0, stream>>>(w.Vf, x, g2, b2, destf, destb);
}

extern "C" void kernel_launch(void* const* d_in, const int* in_sizes, int n_in,
                              void* d_out, int out_size, void* d_ws, size_t ws_size,
                              hipStream_t stream) {
    (void)in_sizes; (void)n_in; (void)out_size; (void)ws_size;
    const float* f0in = (const float*)d_in[0];
    const float* f1in = (const float*)d_in[1];
    const float* WqA = (const float*)d_in[2];
    const float* WkA = (const float*)d_in[3];
    const float* WvA = (const float*)d_in[4];
    const float* WmA = (const float*)d_in[5];
    const float* W1A = (const float*)d_in[6];
    const float* W2A = (const float*)d_in[7];
    const float* g1A = (const float*)d_in[8];
    const float* b1A = (const float*)d_in[9];
    const float* g2A = (const float*)d_in[10];
    const float* b2A = (const float*)d_in[11];

    float* out0 = (float*)d_out;
    float* out1 = out0 + (size_t)RTOT * CDIM;

    const size_t RC = (size_t)RTOT * CDIM;
    float* wsf = (float*)d_ws;
    Ws w;
    w.Q    = wsf;                       // RC
    w.Kf   = w.Q + RC;                  // RC
    w.Vf   = w.Kf + RC;                 // RC
    w.tmp0 = w.Vf + RC;                 // RC
    w.KVp  = w.tmp0 + RC;               // 32*SEG*1024
    w.Ksp  = w.KVp + 32 * SEG * 1024;   // 32*SEG*32
    w.KV   = w.Ksp + 32 * SEG * 32;     // 32*1024
    w.Ksum = w.KV + 32 * 1024;          // 32*32
    ushort* wsb = (ushort*)(w.Ksum + 32 * 32);
    w.msgb = wsb;                       // RC
    w.mlnb = w.msgb + RC;               // RC
    w.h1b  = w.mlnb + RC;               // R*512
    w.xb0  = w.h1b + (size_t)RTOT * 512;// RC
    w.xb1  = w.xb0 + RC;                // RC
    w.WqT  = w.xb1 + RC;                // 8*256*256
    w.WkT  = w.WqT + 8 * 65536;
    w.WvT  = w.WkT + 8 * 65536;
    w.WmT  = w.WvT + 8 * 65536;
    w.W1T  = w.WmT + 8 * 65536;         // 8*512*512
    w.W2T  = w.W1T + 8 * 262144;        // 8*256*512

    const dim3 blk(256);
    // weights: transpose + bf16 convert, all 8 layers per launch
    wconv_t<<<dim3(8, 8, 8), blk, 0, stream>>>(WqA, w.WqT, 256, 256);
    wconv_t<<<dim3(8, 8, 8), blk, 0, stream>>>(WkA, w.WkT, 256, 256);
    wconv_t<<<dim3(8, 8, 8), blk, 0, stream>>>(WvA, w.WvT, 256, 256);
    wconv_t<<<dim3(8, 8, 8), blk, 0, stream>>>(WmA, w.WmT, 256, 256);
    wconv_t<<<dim3(16, 16, 8), blk, 0, stream>>>(W1A, w.W1T, 512, 512);
    wconv_t<<<dim3(8, 16, 8), blk, 0, stream>>>(W2A, w.W2T, 512, 256);

    const dim3 cg(RC / 1024);
    copy2_k<<<cg, blk, 0, stream>>>(f0in, out0, w.xb0);
    copy2_k<<<cg, blk, 0, stream>>>(f1in, out1, w.xb1);

    for (int l = 0; l < 8; ++l) {
        const ushort* WqT = w.WqT + (size_t)l * 65536;
        const ushort* WkT = w.WkT + (size_t)l * 65536;
        const ushort* WvT = w.WvT + (size_t)l * 65536;
        const ushort* WmT = w.WmT + (size_t)l * 65536;
        const ushort* W1T = w.W1T + (size_t)l * 262144;
        const ushort* W2T = w.W2T + (size_t)l * 131072;
        const float* g1 = g1A + l * 256;
        const float* b1 = b1A + l * 256;
        const float* g2 = g2A + l * 256;
        const float* b2 = b2A + l * 256;
        if ((l & 1) == 0) {
            // self
            encoder_layer(out0, w.xb0, w.xb0, out0, w.xb0, WqT, WkT, WvT, WmT, W1T, W2T, g1, b1, g2, b2, w, stream);
            encoder_layer(out1, w.xb1, w.xb1, out1, w.xb1, WqT, WkT, WvT, WmT, W1T, W2T, g1, b1, g2, b2, w, stream);
        } else {
            // cross: new0 = layer(f0, f1) -> tmp0 (bf16 scrap to msgb); f1 = layer(f1, f0_old); f0 = tmp0
            encoder_layer(out0, w.xb0, w.xb1, w.tmp0, w.msgb, WqT, WkT, WvT, WmT, W1T, W2T, g1, b1, g2, b2, w, stream);
            encoder_layer(out1, w.xb1, w.xb0, out1, w.xb1, WqT, WkT, WvT, WmT, W1T, W2T, g1, b1, g2, b2, w, stream);
            copy2_k<<<cg, blk, 0, stream>>>(w.tmp0, out0, w.xb0);
        }
    }
}

// Round 3
// 2155.709 us; speedup vs baseline: 3.6778x; 1.2579x over previous
//
#include <hip/hip_runtime.h>
#include <math.h>

#define RTOT 19200          // 4*4800 rows
#define CDIM 256
#define SLEN 4800
#define NBATCH 4
#define NHEAD 8
#define HDIM 32
#define SEG 20
#define SCHUNK (SLEN/SEG)   // 240

typedef __attribute__((ext_vector_type(8))) short short8v;
typedef __attribute__((ext_vector_type(4))) float f32x4;

__device__ __forceinline__ ushort f2b(float f) {           // fp32 -> bf16 RNE
    unsigned u = __float_as_uint(f);
    unsigned r = (u + 0x7FFFu + ((u >> 16) & 1u)) >> 16;
    return (ushort)r;
}
__device__ __forceinline__ float b2f(ushort u) {
    return __uint_as_float(((unsigned)u) << 16);
}

template<int ACT> __device__ __forceinline__ float actf(float v) {
    if (ACT == 1) return v > 0.0f ? v + 1.0f : __expf(v);   // elu(x)+1
    if (ACT == 2) return v > 0.0f ? v : 0.0f;               // relu
    return v;
}

__device__ __forceinline__ void gload16(const void* g, void* l) {
    __builtin_amdgcn_global_load_lds((const __attribute__((address_space(1))) void*)g,
                                     (__attribute__((address_space(3))) void*)l, 16, 0, 0);
}

// ---------------- bf16 MFMA GEMM ----------------
// C = act(A[M,K] @ B[K,N]); A bf16 row-major (lda), Bt bf16 [N][K].
// CONCAT: A = concat(A, A2) along K, both lda.
// OMODE 0: single bf16 out O0[M][N], activation ACT.
// OMODE 1: qkv split: cols 0-255 -> O0 (elu+1), 256-511 -> O1 (elu+1), 512-767 -> O2 (none); row stride 256.
// OMODE 2: kv split: cols 0-255 -> O0 (elu+1), 256-511 -> O1 (none); row stride 256.
template<int ACT, bool CONCAT, int OMODE>
__global__ __launch_bounds__(256) void gemm_bf16(
    const ushort* __restrict__ A, const ushort* __restrict__ A2, int lda,
    const ushort* __restrict__ Bt,
    ushort* __restrict__ O0, ushort* __restrict__ O1, ushort* __restrict__ O2,
    int N, int K)
{
    __shared__ __align__(16) ushort As[128 * 32];
    __shared__ __align__(16) ushort Bs[128 * 32];
    const int t = threadIdx.x;
    const int wave = t >> 6, lane = t & 63;
    const int bm = blockIdx.y * 128, bn = blockIdx.x * 128;
    const int wr = wave >> 1, wc = wave & 1;
    const int lr = lane & 15, lk = (lane >> 4) * 8;

    const int srow = t >> 2;
    const int sgrp = ((t & 3) * 8) ^ ((srow & 3) * 8);
    const ushort* bAr = A + (size_t)(bm + srow) * lda + sgrp;
    const ushort* bA2r = CONCAT ? (A2 + (size_t)(bm + srow) * lda + sgrp) : (const ushort*)0;
    const ushort* bBr = Bt + (size_t)(bn + srow) * K + sgrp;
    char* ldsA = (char*)As + wave * 1024;
    char* ldsB = (char*)Bs + wave * 1024;
    const size_t a64 = (size_t)64 * lda;
    const size_t b64 = (size_t)64 * K;

    const f32x4 z4 = {0.f, 0.f, 0.f, 0.f};
    f32x4 acc[4][4];
    #pragma unroll
    for (int m = 0; m < 4; ++m)
        #pragma unroll
        for (int n = 0; n < 4; ++n) acc[m][n] = z4;

    for (int k0 = 0; k0 < K; k0 += 32) {
        const ushort* ga;
        if (CONCAT) ga = (k0 < 256) ? (bAr + k0) : (bA2r + (k0 - 256));
        else        ga = bAr + k0;
        gload16(ga, ldsA);
        gload16(ga + a64, ldsA + 4096);
        gload16(bBr + k0, ldsB);
        gload16(bBr + k0 + b64, ldsB + 4096);
        __syncthreads();

        short8v af[4], bfr[4];
        #pragma unroll
        for (int m = 0; m < 4; ++m) {
            const int r = wr * 64 + m * 16 + lr;
            af[m] = *(const short8v*)&As[r * 32 + (lk ^ ((r & 3) * 8))];
        }
        #pragma unroll
        for (int n = 0; n < 4; ++n) {
            const int r = wc * 64 + n * 16 + lr;
            bfr[n] = *(const short8v*)&Bs[r * 32 + (lk ^ ((r & 3) * 8))];
        }
        #pragma unroll
        for (int m = 0; m < 4; ++m)
            #pragma unroll
            for (int n = 0; n < 4; ++n)
                acc[m][n] = __builtin_amdgcn_mfma_f32_16x16x32_bf16(af[m], bfr[n], acc[m][n], 0, 0, 0);
        __syncthreads();
    }

    // C/D: col = lane&15, row = (lane>>4)*4 + j
    const int orow = bm + wr * 64 + (lane >> 4) * 4;
    const int ocol = bn + wc * 64 + lr;
    #pragma unroll
    for (int m = 0; m < 4; ++m)
        #pragma unroll
        for (int n = 0; n < 4; ++n)
            #pragma unroll
            for (int j = 0; j < 4; ++j) {
                const float v = acc[m][n][j];
                const size_t row = (size_t)(orow + m * 16 + j);
                const int col = ocol + n * 16;
                if (OMODE == 0) {
                    O0[row * N + col] = f2b(actf<ACT>(v));
                } else if (OMODE == 1) {
                    const int seg = col >> 8, c = col & 255;
                    ushort* dst = seg == 0 ? O0 : (seg == 1 ? O1 : O2);
                    dst[row * 256 + c] = f2b(seg < 2 ? actf<1>(v) : v);
                } else {
                    const int seg = col >> 8, c = col & 255;
                    ushort* dst = seg == 0 ? O0 : O1;
                    dst[row * 256 + c] = f2b(seg == 0 ? actf<1>(v) : v);
                }
            }
}

// ---------------- weight transpose + bf16 convert: src [L][R][C] -> dst [L(dstride)][C][R] ----------------
__global__ __launch_bounds__(256) void wconv_t(
    const float* __restrict__ src, ushort* __restrict__ dst, int R, int C, size_t dstride)
{
    __shared__ float tile[32][33];
    const int l = blockIdx.z;
    const int r0 = blockIdx.y * 32, c0 = blockIdx.x * 32;
    const int tx = threadIdx.x & 31, ty = threadIdx.x >> 5;
    const float* s = src + (size_t)l * R * C;
    ushort* d = dst + (size_t)l * dstride;
    for (int i = ty; i < 32; i += 8) tile[i][tx] = s[(size_t)(r0 + i) * C + c0 + tx];
    __syncthreads();
    for (int i = ty; i < 32; i += 8) d[(size_t)(c0 + i) * R + r0 + tx] = f2b(tile[tx][i]);
}

// ---------------- KV partial reduction (bf16 in, fp32 partials) ----------------
__global__ __launch_bounds__(256) void kv_part_k(
    const ushort* __restrict__ Kb, const ushort* __restrict__ Vb,
    float* __restrict__ KVp, float* __restrict__ Ksp)
{
    const int blk = blockIdx.x;
    const int seg = blk % SEG;
    const int h = (blk / SEG) % NHEAD;
    const int n = blk / (SEG * NHEAD);
    const int s0 = seg * SCHUNK;
    __shared__ float Ks[8][32];
    __shared__ float Vs[8][32];
    const int t = threadIdx.x;
    const int v0 = (t * 4) & 31;
    const int d = (t * 4) >> 5;
    float acc0 = 0, acc1 = 0, acc2 = 0, acc3 = 0;
    float ksum = 0;
    for (int c = 0; c < SCHUNK; c += 8) {
        const int ss = t >> 5, col = t & 31;
        const size_t row = (size_t)(n * SLEN + s0 + c + ss);
        const size_t off = row * CDIM + h * HDIM + col;
        Ks[ss][col] = b2f(Kb[off]);
        Vs[ss][col] = b2f(Vb[off]);
        __syncthreads();
        #pragma unroll
        for (int q = 0; q < 8; ++q) {
            float kd = Ks[q][d];
            acc0 += kd * Vs[q][v0 + 0];
            acc1 += kd * Vs[q][v0 + 1];
            acc2 += kd * Vs[q][v0 + 2];
            acc3 += kd * Vs[q][v0 + 3];
        }
        if (t < 32) {
            #pragma unroll
            for (int q = 0; q < 8; ++q) ksum += Ks[q][t];
        }
        __syncthreads();
    }
    float* kvp = KVp + ((size_t)((n * NHEAD + h) * SEG + seg)) * 1024;
    kvp[t * 4 + 0] = acc0;
    kvp[t * 4 + 1] = acc1;
    kvp[t * 4 + 2] = acc2;
    kvp[t * 4 + 3] = acc3;
    if (t < 32) Ksp[((size_t)((n * NHEAD + h) * SEG + seg)) * 32 + t] = ksum;
}

// ---------------- KV reduce -> bf16 transposed KV + Ksum B-tiles ----------------
// KVbT[nh][v*32+d] = sum_seg KVp[nh][seg][d*32+v]
// Ksb [nh][c*32+d] = (c==0) ? sum_seg Ksp[nh][seg][d] : 0      (c in 0..15)
__global__ __launch_bounds__(256) void kv_reduce_k(
    const float* __restrict__ KVp, const float* __restrict__ Ksp,
    ushort* __restrict__ KVbT, ushort* __restrict__ Ksb)
{
    const int nh = blockIdx.x;
    const int t = threadIdx.x;
    #pragma unroll
    for (int i = 0; i < 4; ++i) {
        const int idx = t * 4 + i;
        const int v = idx >> 5, d = idx & 31;
        float s = 0;
        for (int seg = 0; seg < SEG; ++seg)
            s += KVp[((size_t)(nh * SEG + seg)) * 1024 + d * 32 + v];
        KVbT[(size_t)nh * 1024 + idx] = f2b(s);
    }
    #pragma unroll
    for (int i = 0; i < 2; ++i) {
        const int idx = t * 2 + i;
        const int c = idx >> 5, d = idx & 31;
        float s = 0;
        if (c == 0)
            for (int seg = 0; seg < SEG; ++seg)
                s += Ksp[((size_t)(nh * SEG + seg)) * 32 + d];
        Ksb[(size_t)nh * 512 + idx] = f2b(s);
    }
}

// ---------------- attention message via MFMA ----------------
// per (n, 64-row block): each wave does 16 rows; per head: msg_tile = Q_h @ KV_h^T tiles, z via Ksum tile
__global__ __launch_bounds__(256) void attn_mfma(
    const ushort* __restrict__ Qb, const ushort* __restrict__ KVbT,
    const ushort* __restrict__ Ksb, ushort* __restrict__ msg)
{
    const int n = blockIdx.y;
    const int t = threadIdx.x, wave = t >> 6, lane = t & 63;
    const int rw = blockIdx.x * 64 + wave * 16;           // wave's 16 rows (within n)
    const int lr = lane & 15, kg = lane >> 4;
    const size_t qrow = ((size_t)n * SLEN + rw + lr) * CDIM;
    const f32x4 z4 = {0.f, 0.f, 0.f, 0.f};
    #pragma unroll
    for (int h = 0; h < NHEAD; ++h) {
        const short8v af = *(const short8v*)&Qb[qrow + h * 32 + kg * 8];
        const ushort* bb = KVbT + ((size_t)(n * NHEAD + h)) * 1024;
        const short8v b0 = *(const short8v*)&bb[lr * 32 + kg * 8];
        const short8v b1 = *(const short8v*)&bb[(16 + lr) * 32 + kg * 8];
        const short8v bz = *(const short8v*)&Ksb[((size_t)(n * NHEAD + h)) * 512 + lr * 32 + kg * 8];
        f32x4 a0 = __builtin_amdgcn_mfma_f32_16x16x32_bf16(af, b0, z4, 0, 0, 0);
        f32x4 a1 = __builtin_amdgcn_mfma_f32_16x16x32_bf16(af, b1, z4, 0, 0, 0);
        f32x4 az = __builtin_amdgcn_mfma_f32_16x16x32_bf16(af, bz, z4, 0, 0, 0);
        #pragma unroll
        for (int j = 0; j < 4; ++j) {
            const float zj = __shfl(az[j], lane & 48);    // col 0 of tile holds z
            const float rz = 1.0f / (zj + 1e-6f);
            const size_t orow = ((size_t)n * SLEN + rw + kg * 4 + j) * CDIM + h * 32;
            msg[orow + lr]      = f2b(a0[j] * rz);
            msg[orow + 16 + lr] = f2b(a1[j] * rz);
        }
    }
}

// ---------------- LayerNorm, bf16 input (optional fp32 residual; fp32/bf16 outs) ----------------
template<bool RES, bool OF>
__global__ __launch_bounds__(256) void ln_k(
    const ushort* __restrict__ X, const float* __restrict__ resid,
    const float* __restrict__ g, const float* __restrict__ b,
    float* __restrict__ outf, ushort* __restrict__ outb)
{
    const int lane = threadIdx.x & 63;
    const size_t row = (size_t)blockIdx.x * 4 + (threadIdx.x >> 6);
    const ushort4 xu = *(const ushort4*)&X[row * CDIM + lane * 4];
    float4 x;
    x.x = b2f(xu.x); x.y = b2f(xu.y); x.z = b2f(xu.z); x.w = b2f(xu.w);
    float s = x.x + x.y + x.z + x.w;
    #pragma unroll
    for (int off = 32; off > 0; off >>= 1) s += __shfl_xor(s, off);
    const float mu = s * (1.0f / 256.0f);
    float cx = x.x - mu, cy = x.y - mu, cz = x.z - mu, cw = x.w - mu;
    float sq = cx * cx + cy * cy + cz * cz + cw * cw;
    #pragma unroll
    for (int off = 32; off > 0; off >>= 1) sq += __shfl_xor(sq, off);
    const float inv = rsqrtf(sq * (1.0f / 256.0f) + 1e-5f);
    float4 gv = *(const float4*)&g[lane * 4];
    float4 bv = *(const float4*)&b[lane * 4];
    float4 o;
    o.x = cx * inv * gv.x + bv.x;
    o.y = cy * inv * gv.y + bv.y;
    o.z = cz * inv * gv.z + bv.z;
    o.w = cw * inv * gv.w + bv.w;
    if (RES) {
        float4 rv = *(const float4*)&resid[row * CDIM + lane * 4];
        o.x += rv.x; o.y += rv.y; o.z += rv.z; o.w += rv.w;
    }
    if (OF) *(float4*)&outf[row * CDIM + lane * 4] = o;
    ushort4 ob = make_ushort4(f2b(o.x), f2b(o.y), f2b(o.z), f2b(o.w));
    *(ushort4*)&outb[row * CDIM + lane * 4] = ob;
}

// copy fp32 -> fp32 + bf16 mirror
__global__ __launch_bounds__(256) void copy2_k(
    const float* __restrict__ src, float* __restrict__ dstf, ushort* __restrict__ dstb)
{
    const size_t i = ((size_t)blockIdx.x * 256 + threadIdx.x) * 4;
    float4 v = *(const float4*)&src[i];
    *(float4*)&dstf[i] = v;
    ushort4 ob = make_ushort4(f2b(v.x), f2b(v.y), f2b(v.z), f2b(v.w));
    *(ushort4*)&dstb[i] = ob;
}

// ---------------- host-side orchestration ----------------
struct Ws {
    float *tmp0, *KVp, *Ksp;
    ushort *Qb, *Kb, *Vb, *msgb, *h1b, *xb0, *xb1, *KVbT, *Ksb;
    ushort *WqkvT, *WmT, *W1T, *W2T;
};

static void encoder_layer(const float* x, const ushort* xb, const ushort* srcb, bool self,
                          float* destf, ushort* destb,
                          const ushort* WqkvT, const ushort* WmT,
                          const ushort* W1T, const ushort* W2T,
                          const float* g1, const float* b1,
                          const float* g2, const float* b2,
                          const Ws& w, hipStream_t stream)
{
    const dim3 blk(256);
    const dim3 g2d(2, RTOT / 128);
    const dim3 g4d(4, RTOT / 128);
    const dim3 g6d(6, RTOT / 128);
    ushort* mWb = w.Kb;   // alias: K dead after kv_part
    ushort* h2b = w.Vb;   // alias: V dead after kv_part
    ushort* mlnb = w.msgb; // alias: msg dead after Wm GEMM (ln1 reads mWb, writes here)

    if (self) {
        // Q|K|V = split(xb @ [Wq|Wk|Wv])
        gemm_bf16<0, false, 1><<<g6d, blk, 0, stream>>>(xb, nullptr, 256, WqkvT, w.Qb, w.Kb, w.Vb, 768, 256);
    } else {
        gemm_bf16<1, false, 0><<<g2d, blk, 0, stream>>>(xb,   nullptr, 256, WqkvT,             w.Qb, nullptr, nullptr, 256, 256);
        gemm_bf16<0, false, 2><<<g4d, blk, 0, stream>>>(srcb, nullptr, 256, WqkvT + 256 * 256, w.Kb, w.Vb,   nullptr, 512, 256);
    }
    kv_part_k<<<dim3(NBATCH * NHEAD * SEG), blk, 0, stream>>>(w.Kb, w.Vb, w.KVp, w.Ksp);
    kv_reduce_k<<<dim3(NBATCH * NHEAD), blk, 0, stream>>>(w.KVp, w.Ksp, w.KVbT, w.Ksb);
    attn_mfma<<<dim3(SLEN / 64, NBATCH), blk, 0, stream>>>(w.Qb, w.KVbT, w.Ksb, w.msgb);
    // msgW = msg @ Wm (bf16)
    gemm_bf16<0, false, 0><<<g2d, blk, 0, stream>>>(w.msgb, nullptr, 256, WmT, mWb, nullptr, nullptr, 256, 256);
    // msgln = LN(msgW)
    ln_k<false, false><<<dim3(RTOT / 4), blk, 0, stream>>>(mWb, nullptr, g1, b1, nullptr, mlnb);
    // h1 = relu(concat(xb, mlnb) @ W1)
    gemm_bf16<2, true, 0><<<g4d, blk, 0, stream>>>(xb, mlnb, 256, W1T, w.h1b, nullptr, nullptr, 512, 512);
    // h2 = h1 @ W2
    gemm_bf16<0, false, 0><<<g2d, blk, 0, stream>>>(w.h1b, nullptr, 512, W2T, h2b, nullptr, nullptr, 256, 512);
    // dest = x + LN(h2)
    ln_k<true, true><<<dim3(RTOT / 4), blk, 0, stream>>>(h2b, x, g2, b2, destf, destb);
}

extern "C" void kernel_launch(void* const* d_in, const int* in_sizes, int n_in,
                              void* d_out, int out_size, void* d_ws, size_t ws_size,
                              hipStream_t stream) {
    (void)in_sizes; (void)n_in; (void)out_size; (void)ws_size;
    const float* f0in = (const float*)d_in[0];
    const float* f1in = (const float*)d_in[1];
    const float* WqA = (const float*)d_in[2];
    const float* WkA = (const float*)d_in[3];
    const float* WvA = (const float*)d_in[4];
    const float* WmA = (const float*)d_in[5];
    const float* W1A = (const float*)d_in[6];
    const float* W2A = (const float*)d_in[7];
    const float* g1A = (const float*)d_in[8];
    const float* b1A = (const float*)d_in[9];
    const float* g2A = (const float*)d_in[10];
    const float* b2A = (const float*)d_in[11];

    float* out0 = (float*)d_out;
    float* out1 = out0 + (size_t)RTOT * CDIM;

    const size_t RC = (size_t)RTOT * CDIM;
    float* wsf = (float*)d_ws;
    Ws w;
    w.tmp0 = wsf;                       // RC fp32
    w.KVp  = w.tmp0 + RC;               // 32*SEG*1024 fp32
    w.Ksp  = w.KVp + 32 * SEG * 1024;   // 32*SEG*32 fp32
    ushort* wsb = (ushort*)(w.Ksp + 32 * SEG * 32);
    w.Qb   = wsb;                       // RC
    w.Kb   = w.Qb + RC;                 // RC
    w.Vb   = w.Kb + RC;                 // RC
    w.msgb = w.Vb + RC;                 // RC
    w.h1b  = w.msgb + RC;               // R*512
    w.xb0  = w.h1b + (size_t)RTOT * 512;// RC
    w.xb1  = w.xb0 + RC;                // RC
    w.KVbT = w.xb1 + RC;                // 32*1024
    w.Ksb  = w.KVbT + 32 * 1024;        // 32*512
    w.WqkvT = w.Ksb + 32 * 512;         // 8 * 768*256
    w.WmT  = w.WqkvT + (size_t)8 * 768 * 256;  // 8*256*256
    w.W1T  = w.WmT + (size_t)8 * 65536;        // 8*512*512
    w.W2T  = w.W1T + (size_t)8 * 262144;       // 8*256*512

    const dim3 blk(256);
    // weights: transpose + bf16 convert; Wq/Wk/Wv packed per layer into [768][256]
    wconv_t<<<dim3(8, 8, 8), blk, 0, stream>>>(WqA, w.WqkvT,              256, 256, 768 * 256);
    wconv_t<<<dim3(8, 8, 8), blk, 0, stream>>>(WkA, w.WqkvT + 256 * 256,  256, 256, 768 * 256);
    wconv_t<<<dim3(8, 8, 8), blk, 0, stream>>>(WvA, w.WqkvT + 512 * 256,  256, 256, 768 * 256);
    wconv_t<<<dim3(8, 8, 8), blk, 0, stream>>>(WmA, w.WmT, 256, 256, 65536);
    wconv_t<<<dim3(16, 16, 8), blk, 0, stream>>>(W1A, w.W1T, 512, 512, 262144);
    wconv_t<<<dim3(8, 16, 8), blk, 0, stream>>>(W2A, w.W2T, 512, 256, 131072);

    const dim3 cg(RC / 1024);
    copy2_k<<<cg, blk, 0, stream>>>(f0in, out0, w.xb0);
    copy2_k<<<cg, blk, 0, stream>>>(f1in, out1, w.xb1);

    for (int l = 0; l < 8; ++l) {
        const ushort* WqkvT = w.WqkvT + (size_t)l * 768 * 256;
        const ushort* WmT = w.WmT + (size_t)l * 65536;
        const ushort* W1T = w.W1T + (size_t)l * 262144;
        const ushort* W2T = w.W2T + (size_t)l * 131072;
        const float* g1 = g1A + l * 256;
        const float* b1 = b1A + l * 256;
        const float* g2 = g2A + l * 256;
        const float* b2 = b2A + l * 256;
        if ((l & 1) == 0) {
            // self
            encoder_layer(out0, w.xb0, w.xb0, true, out0, w.xb0, WqkvT, WmT, W1T, W2T, g1, b1, g2, b2, w, stream);
            encoder_layer(out1, w.xb1, w.xb1, true, out1, w.xb1, WqkvT, WmT, W1T, W2T, g1, b1, g2, b2, w, stream);
        } else {
            // cross: new0 = layer(f0, f1) -> tmp0 (bf16 dest is scratch); f1 = layer(f1, f0_old); f0 = tmp0
            encoder_layer(out0, w.xb0, w.xb1, false, w.tmp0, w.msgb, WqkvT, WmT, W1T, W2T, g1, b1, g2, b2, w, stream);
            encoder_layer(out1, w.xb1, w.xb0, false, out1, w.xb1, WqkvT, WmT, W1T, W2T, g1, b1, g2, b2, w, stream);
            copy2_k<<<cg, blk, 0, stream>>>(w.tmp0, out0, w.xb0);
        }
    }
}

// Round 4
// 1599.884 us; speedup vs baseline: 4.9555x; 1.3474x over previous
//
#include <hip/hip_runtime.h>
#include <math.h>

#define RTOT 19200          // rows per feature map (4*4800)
#define RALL 38400          // both feature maps batched
#define CDIM 256
#define SLEN 4800
#define NB 8                // total batches (4 per map; 0-3 = feat0, 4-7 = feat1)
#define NHEAD 8
#define HDIM 32
#define SEG 25
#define SCHUNK 192          // SLEN/SEG

typedef __attribute__((ext_vector_type(8))) short short8v;
typedef __attribute__((ext_vector_type(4))) float f32x4;

__device__ __forceinline__ ushort f2b(float f) {           // fp32 -> bf16 RNE
    unsigned u = __float_as_uint(f);
    unsigned r = (u + 0x7FFFu + ((u >> 16) & 1u)) >> 16;
    return (ushort)r;
}
__device__ __forceinline__ float b2f(ushort u) {
    return __uint_as_float(((unsigned)u) << 16);
}

template<int ACT> __device__ __forceinline__ float actf(float v) {
    if (ACT == 1) return v > 0.0f ? v + 1.0f : __expf(v);   // elu(x)+1
    if (ACT == 2) return v > 0.0f ? v : 0.0f;               // relu
    return v;
}

__device__ __forceinline__ void gload16(const void* g, void* l) {
    __builtin_amdgcn_global_load_lds((const __attribute__((address_space(1))) void*)g,
                                     (__attribute__((address_space(3))) void*)l, 16, 0, 0);
}

// ---------------- bf16 MFMA GEMM (128x128 tile) ----------------
// OMODE 0: single out O0[M][N] with ACT.
// OMODE 1: qkv split: cols 0-255 -> O0 (elu+1), 256-511 -> O1 (elu+1), 512-767 -> O2 (none); row stride 256.
template<int ACT, bool CONCAT, int OMODE>
__global__ __launch_bounds__(256) void gemm_bf16(
    const ushort* __restrict__ A, const ushort* __restrict__ A2, int lda,
    const ushort* __restrict__ Bt,
    ushort* __restrict__ O0, ushort* __restrict__ O1, ushort* __restrict__ O2,
    int N, int K)
{
    __shared__ __align__(16) ushort As[128 * 32];
    __shared__ __align__(16) ushort Bs[128 * 32];
    const int t = threadIdx.x;
    const int wave = t >> 6, lane = t & 63;
    const int bm = blockIdx.y * 128, bn = blockIdx.x * 128;
    const int wr = wave >> 1, wc = wave & 1;
    const int lr = lane & 15, lk = (lane >> 4) * 8;

    const int srow = t >> 2;
    const int sgrp = ((t & 3) * 8) ^ ((srow & 3) * 8);
    const ushort* bAr = A + (size_t)(bm + srow) * lda + sgrp;
    const ushort* bA2r = CONCAT ? (A2 + (size_t)(bm + srow) * lda + sgrp) : (const ushort*)0;
    const ushort* bBr = Bt + (size_t)(bn + srow) * K + sgrp;
    char* ldsA = (char*)As + wave * 1024;
    char* ldsB = (char*)Bs + wave * 1024;
    const size_t a64 = (size_t)64 * lda;
    const size_t b64 = (size_t)64 * K;

    const f32x4 z4 = {0.f, 0.f, 0.f, 0.f};
    f32x4 acc[4][4];
    #pragma unroll
    for (int m = 0; m < 4; ++m)
        #pragma unroll
        for (int n = 0; n < 4; ++n) acc[m][n] = z4;

    for (int k0 = 0; k0 < K; k0 += 32) {
        const ushort* ga;
        if (CONCAT) ga = (k0 < 256) ? (bAr + k0) : (bA2r + (k0 - 256));
        else        ga = bAr + k0;
        gload16(ga, ldsA);
        gload16(ga + a64, ldsA + 4096);
        gload16(bBr + k0, ldsB);
        gload16(bBr + k0 + b64, ldsB + 4096);
        __syncthreads();

        short8v af[4], bfr[4];
        #pragma unroll
        for (int m = 0; m < 4; ++m) {
            const int r = wr * 64 + m * 16 + lr;
            af[m] = *(const short8v*)&As[r * 32 + (lk ^ ((r & 3) * 8))];
        }
        #pragma unroll
        for (int n = 0; n < 4; ++n) {
            const int r = wc * 64 + n * 16 + lr;
            bfr[n] = *(const short8v*)&Bs[r * 32 + (lk ^ ((r & 3) * 8))];
        }
        #pragma unroll
        for (int m = 0; m < 4; ++m)
            #pragma unroll
            for (int n = 0; n < 4; ++n)
                acc[m][n] = __builtin_amdgcn_mfma_f32_16x16x32_bf16(af[m], bfr[n], acc[m][n], 0, 0, 0);
        __syncthreads();
    }

    const int orow = bm + wr * 64 + (lane >> 4) * 4;
    const int ocol = bn + wc * 64 + lr;
    #pragma unroll
    for (int m = 0; m < 4; ++m)
        #pragma unroll
        for (int n = 0; n < 4; ++n)
            #pragma unroll
            for (int j = 0; j < 4; ++j) {
                const float v = acc[m][n][j];
                const size_t row = (size_t)(orow + m * 16 + j);
                const int col = ocol + n * 16;
                if (OMODE == 0) {
                    O0[row * N + col] = f2b(actf<ACT>(v));
                } else {
                    const int seg = col >> 8, c = col & 255;
                    ushort* dst = seg == 0 ? O0 : (seg == 1 ? O1 : O2);
                    dst[row * 256 + c] = f2b(seg < 2 ? actf<1>(v) : v);
                }
            }
}

// ---------------- GEMM + LayerNorm fused (BM=64, BN=256 full width) ----------------
// out = LN(A @ B) * g + b   [+ resid, fp32 out] ; always bf16 out.
template<bool RES>
__global__ __launch_bounds__(256) void gemm_ln(
    const ushort* __restrict__ A, int lda,
    const ushort* __restrict__ Bt,
    const float* __restrict__ g, const float* __restrict__ bb,
    const float* __restrict__ rx0, const float* __restrict__ rx1,
    float* __restrict__ outf, ushort* __restrict__ outb, int K)
{
    __shared__ __align__(16) ushort As[64 * 32];
    __shared__ __align__(16) ushort Bs[256 * 32];
    __shared__ float red[2][4][64];
    const int t = threadIdx.x;
    const int wave = t >> 6, lane = t & 63;
    const int bm = blockIdx.x * 64;
    const int lr = lane & 15, kg = lane >> 4, lk = kg * 8;

    const int srow = t >> 2;
    const int sg = ((t & 3) * 8) ^ ((srow & 3) * 8);
    const ushort* aP = A + (size_t)(bm + srow) * lda + sg;
    const ushort* bP = Bt + (size_t)srow * K + sg;
    char* ldsA = (char*)As + wave * 1024;
    char* ldsB = (char*)Bs + wave * 1024;
    const size_t b64 = (size_t)64 * K;

    const f32x4 z4 = {0.f, 0.f, 0.f, 0.f};
    f32x4 acc[4][4];
    #pragma unroll
    for (int m = 0; m < 4; ++m)
        #pragma unroll
        for (int n = 0; n < 4; ++n) acc[m][n] = z4;

    for (int k0 = 0; k0 < K; k0 += 32) {
        gload16(aP + k0, ldsA);
        gload16(bP + k0, ldsB);
        gload16(bP + k0 + b64, ldsB + 4096);
        gload16(bP + k0 + 2 * b64, ldsB + 8192);
        gload16(bP + k0 + 3 * b64, ldsB + 12288);
        __syncthreads();

        short8v af[4], bfr[4];
        #pragma unroll
        for (int m = 0; m < 4; ++m) {
            const int r = m * 16 + lr;
            af[m] = *(const short8v*)&As[r * 32 + (lk ^ ((r & 3) * 8))];
        }
        #pragma unroll
        for (int n = 0; n < 4; ++n) {
            const int r = wave * 64 + n * 16 + lr;
            bfr[n] = *(const short8v*)&Bs[r * 32 + (lk ^ ((r & 3) * 8))];
        }
        #pragma unroll
        for (int m = 0; m < 4; ++m)
            #pragma unroll
            for (int n = 0; n < 4; ++n)
                acc[m][n] = __builtin_amdgcn_mfma_f32_16x16x32_bf16(af[m], bfr[n], acc[m][n], 0, 0, 0);
        __syncthreads();
    }

    // per-row partial sums over this wave's 64 cols
    #pragma unroll
    for (int m = 0; m < 4; ++m)
        #pragma unroll
        for (int j = 0; j < 4; ++j) {
            float s = 0.f, q = 0.f;
            #pragma unroll
            for (int n = 0; n < 4; ++n) { const float v = acc[m][n][j]; s += v; q += v * v; }
            #pragma unroll
            for (int mk = 1; mk < 16; mk <<= 1) { s += __shfl_xor(s, mk); q += __shfl_xor(q, mk); }
            if (lr == 0) {
                red[0][wave][m * 16 + kg * 4 + j] = s;
                red[1][wave][m * 16 + kg * 4 + j] = q;
            }
        }
    __syncthreads();

    float gv[4], bv[4];
    #pragma unroll
    for (int n = 0; n < 4; ++n) {
        const int col = wave * 64 + n * 16 + lr;
        gv[n] = g[col]; bv[n] = bb[col];
    }
    const float* rxb = (const float*)0;
    if (RES) rxb = (bm < RTOT) ? rx0 + (size_t)bm * CDIM : rx1 + (size_t)(bm - RTOT) * CDIM;

    #pragma unroll
    for (int m = 0; m < 4; ++m)
        #pragma unroll
        for (int j = 0; j < 4; ++j) {
            const int row = m * 16 + kg * 4 + j;
            const float tot = red[0][0][row] + red[0][1][row] + red[0][2][row] + red[0][3][row];
            const float tq  = red[1][0][row] + red[1][1][row] + red[1][2][row] + red[1][3][row];
            const float mu = tot * (1.0f / 256.0f);
            const float var = tq * (1.0f / 256.0f) - mu * mu;
            const float inv = rsqrtf(var + 1e-5f);
            const size_t go = (size_t)(bm + row) * CDIM;
            #pragma unroll
            for (int n = 0; n < 4; ++n) {
                const int col = wave * 64 + n * 16 + lr;
                float val = (acc[m][n][j] - mu) * inv * gv[n] + bv[n];
                if (RES) {
                    val += rxb[(size_t)row * CDIM + col];
                    outf[go + col] = val;
                }
                outb[go + col] = f2b(val);
            }
        }
}

// ---------------- weight transpose + bf16: src [L][R][C] -> dst [L(dstride)][C][R] ----------------
__global__ __launch_bounds__(256) void wconv_t(
    const float* __restrict__ src, ushort* __restrict__ dst, int R, int C, size_t dstride)
{
    __shared__ float tile[32][33];
    const int l = blockIdx.z;
    const int r0 = blockIdx.y * 32, c0 = blockIdx.x * 32;
    const int tx = threadIdx.x & 31, ty = threadIdx.x >> 5;
    const float* s = src + (size_t)l * R * C;
    ushort* d = dst + (size_t)l * dstride;
    for (int i = ty; i < 32; i += 8) tile[i][tx] = s[(size_t)(r0 + i) * C + c0 + tx];
    __syncthreads();
    for (int i = ty; i < 32; i += 8) d[(size_t)(c0 + i) * R + r0 + tx] = f2b(tile[tx][i]);
}

// ---------------- KV partial reduction (bf16 in, fp32 partials) ----------------
__global__ __launch_bounds__(256) void kv_part_k(
    const ushort* __restrict__ Kb, const ushort* __restrict__ Vb,
    float* __restrict__ KVp, float* __restrict__ Ksp)
{
    const int blk = blockIdx.x;
    const int seg = blk % SEG;
    const int h = (blk / SEG) % NHEAD;
    const int n = blk / (SEG * NHEAD);          // 0..7
    const int s0 = seg * SCHUNK;
    __shared__ float Ks[16][32];
    __shared__ float Vs[16][32];
    const int t = threadIdx.x;
    const int rr = t >> 4, c2 = (t & 15) * 2;
    const int d = t >> 3, v0 = (t & 7) * 4;
    float a0 = 0, a1 = 0, a2 = 0, a3 = 0, ksum = 0;
    for (int c = 0; c < SCHUNK; c += 16) {
        const size_t off = ((size_t)(n * SLEN + s0 + c + rr)) * CDIM + h * HDIM + c2;
        const ushort2 ku = *(const ushort2*)&Kb[off];
        const ushort2 vu = *(const ushort2*)&Vb[off];
        Ks[rr][c2] = b2f(ku.x); Ks[rr][c2 + 1] = b2f(ku.y);
        Vs[rr][c2] = b2f(vu.x); Vs[rr][c2 + 1] = b2f(vu.y);
        __syncthreads();
        #pragma unroll
        for (int q = 0; q < 16; ++q) {
            const float kd = Ks[q][d];
            a0 += kd * Vs[q][v0 + 0];
            a1 += kd * Vs[q][v0 + 1];
            a2 += kd * Vs[q][v0 + 2];
            a3 += kd * Vs[q][v0 + 3];
        }
        if (t < 32) {
            #pragma unroll
            for (int q = 0; q < 16; ++q) ksum += Ks[q][t];
        }
        __syncthreads();
    }
    float* kvp = KVp + ((size_t)((n * NHEAD + h) * SEG + seg)) * 1024;
    kvp[t * 4 + 0] = a0;
    kvp[t * 4 + 1] = a1;
    kvp[t * 4 + 2] = a2;
    kvp[t * 4 + 3] = a3;
    if (t < 32) Ksp[((size_t)((n * NHEAD + h) * SEG + seg)) * 32 + t] = ksum;
}

// ---------------- KV reduce -> bf16 transposed KV + Ksum B-tiles ----------------
__global__ __launch_bounds__(256) void kv_reduce_k(
    const float* __restrict__ KVp, const float* __restrict__ Ksp,
    ushort* __restrict__ KVbT, ushort* __restrict__ Ksb)
{
    const int nh = blockIdx.x;      // 0..63
    const int t = threadIdx.x;
    #pragma unroll
    for (int i = 0; i < 4; ++i) {
        const int idx = t * 4 + i;
        const int v = idx >> 5, d = idx & 31;
        float s = 0;
        for (int seg = 0; seg < SEG; ++seg)
            s += KVp[((size_t)(nh * SEG + seg)) * 1024 + d * 32 + v];
        KVbT[(size_t)nh * 1024 + idx] = f2b(s);
    }
    #pragma unroll
    for (int i = 0; i < 2; ++i) {
        const int idx = t * 2 + i;
        const int c = idx >> 5, d = idx & 31;
        float s = 0;
        if (c == 0)
            for (int seg = 0; seg < SEG; ++seg)
                s += Ksp[((size_t)(nh * SEG + seg)) * 32 + d];
        Ksb[(size_t)nh * 512 + idx] = f2b(s);
    }
}

// ---------------- attention message via MFMA (xorv selects cross/self KV source) ----------------
__global__ __launch_bounds__(256) void attn_mfma(
    const ushort* __restrict__ Qb, const ushort* __restrict__ KVbT,
    const ushort* __restrict__ Ksb, ushort* __restrict__ msg, int xorv)
{
    const int n = blockIdx.y;                 // query batch 0..7
    const int src = n ^ xorv;                 // KV source batch
    const int t = threadIdx.x, wave = t >> 6, lane = t & 63;
    const int rw = blockIdx.x * 64 + wave * 16;
    const int lr = lane & 15, kg = lane >> 4;
    const size_t qrow = ((size_t)n * SLEN + rw + lr) * CDIM;
    const f32x4 z4 = {0.f, 0.f, 0.f, 0.f};
    #pragma unroll
    for (int h = 0; h < NHEAD; ++h) {
        const short8v af = *(const short8v*)&Qb[qrow + h * 32 + kg * 8];
        const ushort* bbp = KVbT + ((size_t)(src * NHEAD + h)) * 1024;
        const short8v b0 = *(const short8v*)&bbp[lr * 32 + kg * 8];
        const short8v b1 = *(const short8v*)&bbp[(16 + lr) * 32 + kg * 8];
        const short8v bz = *(const short8v*)&Ksb[((size_t)(src * NHEAD + h)) * 512 + lr * 32 + kg * 8];
        f32x4 a0 = __builtin_amdgcn_mfma_f32_16x16x32_bf16(af, b0, z4, 0, 0, 0);
        f32x4 a1 = __builtin_amdgcn_mfma_f32_16x16x32_bf16(af, b1, z4, 0, 0, 0);
        f32x4 az = __builtin_amdgcn_mfma_f32_16x16x32_bf16(af, bz, z4, 0, 0, 0);
        #pragma unroll
        for (int j = 0; j < 4; ++j) {
            const float zj = __shfl(az[j], lane & 48);
            const float rz = 1.0f / (zj + 1e-6f);
            const size_t orow = ((size_t)n * SLEN + rw + kg * 4 + j) * CDIM + h * 32;
            msg[orow + lr]      = f2b(a0[j] * rz);
            msg[orow + 16 + lr] = f2b(a1[j] * rz);
        }
    }
}

// ---------------- fp32 -> bf16 convert ----------------
__global__ __launch_bounds__(256) void cvt_in_k(const float* __restrict__ src, ushort* __restrict__ dst) {
    const size_t i = ((size_t)blockIdx.x * 256 + threadIdx.x) * 4;
    const float4 v = *(const float4*)&src[i];
    ushort4 ob = make_ushort4(f2b(v.x), f2b(v.y), f2b(v.z), f2b(v.w));
    *(ushort4*)&dst[i] = ob;
}

// ---------------- host-side orchestration ----------------
struct Ws {
    float *xf, *KVp, *Ksp;
    ushort *xb, *Qb, *Kb, *Vb, *h1b, *KVbT, *Ksb;
    ushort *WqkvT, *WmT, *W1T, *W2T;
};

static void layer_pass(const float* rx0, const float* rx1, float* destf, int xorv,
                       const ushort* WqkvT, const ushort* WmT,
                       const ushort* W1T, const ushort* W2T,
                       const float* g1, const float* b1,
                       const float* g2, const float* b2,
                       const Ws& w, hipStream_t stream)
{
    const dim3 blk(256);
    // 1. Q|K|V = split(xb @ [Wq|Wk|Wv]) over all 38400 rows
    gemm_bf16<0, false, 1><<<dim3(6, RALL / 128), blk, 0, stream>>>(
        w.xb, nullptr, 256, WqkvT, w.Qb, w.Kb, w.Vb, 768, 256);
    // 2-3. per-batch KV aggregate (uses pre-layer state for both halves -> cross-safe)
    kv_part_k<<<dim3(NB * NHEAD * SEG), blk, 0, stream>>>(w.Kb, w.Vb, w.KVp, w.Ksp);
    kv_reduce_k<<<dim3(NB * NHEAD), blk, 0, stream>>>(w.KVp, w.Ksp, w.KVbT, w.Ksb);
    // 4. msg -> Vb (raw V dead)
    attn_mfma<<<dim3(SLEN / 64, NB), blk, 0, stream>>>(w.Qb, w.KVbT, w.Ksb, w.Vb, xorv);
    // 5. mln = LN(msg @ Wm) -> Kb (raw K dead)
    gemm_ln<false><<<dim3(RALL / 64), blk, 0, stream>>>(
        w.Vb, 256, WmT, g1, b1, nullptr, nullptr, nullptr, w.Kb, 256);
    // 6. h1 = relu(concat(xb, mln) @ W1)
    gemm_bf16<2, true, 0><<<dim3(4, RALL / 128), blk, 0, stream>>>(
        w.xb, w.Kb, 256, W1T, w.h1b, nullptr, nullptr, 512, 512);
    // 7. x' = resid + LN(h1 @ W2) -> destf (fp32) + xb (bf16, in place)
    gemm_ln<true><<<dim3(RALL / 64), blk, 0, stream>>>(
        w.h1b, 512, W2T, g2, b2, rx0, rx1, destf, w.xb, 512);
}

extern "C" void kernel_launch(void* const* d_in, const int* in_sizes, int n_in,
                              void* d_out, int out_size, void* d_ws, size_t ws_size,
                              hipStream_t stream) {
    (void)in_sizes; (void)n_in; (void)out_size; (void)ws_size;
    const float* f0in = (const float*)d_in[0];
    const float* f1in = (const float*)d_in[1];
    const float* WqA = (const float*)d_in[2];
    const float* WkA = (const float*)d_in[3];
    const float* WvA = (const float*)d_in[4];
    const float* WmA = (const float*)d_in[5];
    const float* W1A = (const float*)d_in[6];
    const float* W2A = (const float*)d_in[7];
    const float* g1A = (const float*)d_in[8];
    const float* b1A = (const float*)d_in[9];
    const float* g2A = (const float*)d_in[10];
    const float* b2A = (const float*)d_in[11];

    float* outf = (float*)d_out;                 // [RALL][256] contiguous = out0 | out1
    const size_t RC = (size_t)RTOT * CDIM;
    const size_t RAC = (size_t)RALL * CDIM;

    float* wsf = (float*)d_ws;
    Ws w;
    w.xf  = wsf;                                  // RAC fp32
    w.KVp = w.xf + RAC;                           // 64*SEG*1024 fp32
    w.Ksp = w.KVp + (size_t)64 * SEG * 1024;      // 64*SEG*32 fp32
    ushort* p = (ushort*)(w.Ksp + 64 * SEG * 32);
    w.xb = p;   p += RAC;
    w.Qb = p;   p += RAC;
    w.Kb = p;   p += RAC;
    w.Vb = p;   p += RAC;
    w.h1b = p;  p += (size_t)RALL * 512;
    w.KVbT = p; p += 64 * 1024;
    w.Ksb = p;  p += 64 * 512;
    w.WqkvT = p; p += (size_t)8 * 768 * 256;
    w.WmT = p;  p += (size_t)8 * 256 * 256;
    w.W1T = p;  p += (size_t)8 * 512 * 512;
    w.W2T = p;  p += (size_t)8 * 512 * 256;

    const dim3 blk(256);
    wconv_t<<<dim3(8, 8, 8), blk, 0, stream>>>(WqA, w.WqkvT,             256, 256, 768 * 256);
    wconv_t<<<dim3(8, 8, 8), blk, 0, stream>>>(WkA, w.WqkvT + 256 * 256, 256, 256, 768 * 256);
    wconv_t<<<dim3(8, 8, 8), blk, 0, stream>>>(WvA, w.WqkvT + 512 * 256, 256, 256, 768 * 256);
    wconv_t<<<dim3(8, 8, 8), blk, 0, stream>>>(WmA, w.WmT, 256, 256, 65536);
    wconv_t<<<dim3(16, 16, 8), blk, 0, stream>>>(W1A, w.W1T, 512, 512, 262144);
    wconv_t<<<dim3(8, 16, 8), blk, 0, stream>>>(W2A, w.W2T, 512, 256, 131072);

    cvt_in_k<<<dim3(RC / 1024), blk, 0, stream>>>(f0in, w.xb);
    cvt_in_k<<<dim3(RC / 1024), blk, 0, stream>>>(f1in, w.xb + RC);

    for (int l = 0; l < 8; ++l) {
        const int xorv = (l & 1) ? 4 : 0;                 // cross layers swap KV source
        const float* rx0 = (l == 0) ? f0in : w.xf;
        const float* rx1 = (l == 0) ? f1in : w.xf + RC;
        float* destf = (l == 7) ? outf : w.xf;
        layer_pass(rx0, rx1, destf, xorv,
                   w.WqkvT + (size_t)l * 768 * 256,
                   w.WmT + (size_t)l * 65536,
                   w.W1T + (size_t)l * 262144,
                   w.W2T + (size_t)l * 131072,
                   g1A + l * 256, b1A + l * 256, g2A + l * 256, b2A + l * 256,
                   w, stream);
    }
}

// Round 5
// 1500.713 us; speedup vs baseline: 5.2829x; 1.0661x over previous
//
#include <hip/hip_runtime.h>
#include <math.h>

#define RTOT 19200          // rows per feature map (4*4800)
#define RALL 38400          // both feature maps batched
#define CDIM 256
#define SLEN 4800
#define NB 8                // total batches (0-3 = feat0, 4-7 = feat1)
#define NHEAD 8
#define HDIM 32
#define SEG 25
#define SCHUNK 192          // SLEN/SEG

typedef __attribute__((ext_vector_type(8))) short short8v;
typedef __attribute__((ext_vector_type(4))) float f32x4;

__device__ __forceinline__ ushort f2b(float f) {           // fp32 -> bf16 RNE
    unsigned u = __float_as_uint(f);
    unsigned r = (u + 0x7FFFu + ((u >> 16) & 1u)) >> 16;
    return (ushort)r;
}
__device__ __forceinline__ float b2f(ushort u) {
    return __uint_as_float(((unsigned)u) << 16);
}

template<int ACT> __device__ __forceinline__ float actf(float v) {
    if (ACT == 1) return v > 0.0f ? v + 1.0f : __expf(v);   // elu(x)+1
    if (ACT == 2) return v > 0.0f ? v : 0.0f;               // relu
    return v;
}

__device__ __forceinline__ void gload16(const void* g, void* l) {
    __builtin_amdgcn_global_load_lds((const __attribute__((address_space(1))) void*)g,
                                     (__attribute__((address_space(3))) void*)l, 16, 0, 0);
}

// ---------------- bf16 MFMA GEMM (128x128 tile) ----------------
// OMODE 0: single out O0[M][N] with ACT.
// OMODE 1: qkv split: cols 0-255 -> O0 (elu+1), 256-511 -> O1 (elu+1), 512-767 -> O2 (none); row stride 256.
template<int ACT, bool CONCAT, int OMODE>
__global__ __launch_bounds__(256) void gemm_bf16(
    const ushort* __restrict__ A, const ushort* __restrict__ A2, int lda,
    const ushort* __restrict__ Bt,
    ushort* __restrict__ O0, ushort* __restrict__ O1, ushort* __restrict__ O2,
    int N, int K)
{
    __shared__ __align__(16) ushort As[128 * 32];
    __shared__ __align__(16) ushort Bs[128 * 32];
    const int t = threadIdx.x;
    const int wave = t >> 6, lane = t & 63;
    const int bm = blockIdx.y * 128, bn = blockIdx.x * 128;
    const int wr = wave >> 1, wc = wave & 1;
    const int lr = lane & 15, lk = (lane >> 4) * 8;

    const int srow = t >> 2;
    const int sgrp = ((t & 3) * 8) ^ ((srow & 3) * 8);
    const ushort* bAr = A + (size_t)(bm + srow) * lda + sgrp;
    const ushort* bA2r = CONCAT ? (A2 + (size_t)(bm + srow) * lda + sgrp) : (const ushort*)0;
    const ushort* bBr = Bt + (size_t)(bn + srow) * K + sgrp;
    char* ldsA = (char*)As + wave * 1024;
    char* ldsB = (char*)Bs + wave * 1024;
    const size_t a64 = (size_t)64 * lda;
    const size_t b64 = (size_t)64 * K;

    const f32x4 z4 = {0.f, 0.f, 0.f, 0.f};
    f32x4 acc[4][4];
    #pragma unroll
    for (int m = 0; m < 4; ++m)
        #pragma unroll
        for (int n = 0; n < 4; ++n) acc[m][n] = z4;

    for (int k0 = 0; k0 < K; k0 += 32) {
        const ushort* ga;
        if (CONCAT) ga = (k0 < 256) ? (bAr + k0) : (bA2r + (k0 - 256));
        else        ga = bAr + k0;
        gload16(ga, ldsA);
        gload16(ga + a64, ldsA + 4096);
        gload16(bBr + k0, ldsB);
        gload16(bBr + k0 + b64, ldsB + 4096);
        __syncthreads();

        short8v af[4], bfr[4];
        #pragma unroll
        for (int m = 0; m < 4; ++m) {
            const int r = wr * 64 + m * 16 + lr;
            af[m] = *(const short8v*)&As[r * 32 + (lk ^ ((r & 3) * 8))];
        }
        #pragma unroll
        for (int n = 0; n < 4; ++n) {
            const int r = wc * 64 + n * 16 + lr;
            bfr[n] = *(const short8v*)&Bs[r * 32 + (lk ^ ((r & 3) * 8))];
        }
        #pragma unroll
        for (int m = 0; m < 4; ++m)
            #pragma unroll
            for (int n = 0; n < 4; ++n)
                acc[m][n] = __builtin_amdgcn_mfma_f32_16x16x32_bf16(af[m], bfr[n], acc[m][n], 0, 0, 0);
        __syncthreads();
    }

    const int orow = bm + wr * 64 + (lane >> 4) * 4;
    const int ocol = bn + wc * 64 + lr;
    #pragma unroll
    for (int m = 0; m < 4; ++m)
        #pragma unroll
        for (int n = 0; n < 4; ++n)
            #pragma unroll
            for (int j = 0; j < 4; ++j) {
                const float v = acc[m][n][j];
                const size_t row = (size_t)(orow + m * 16 + j);
                const int col = ocol + n * 16;
                if (OMODE == 0) {
                    O0[row * N + col] = f2b(actf<ACT>(v));
                } else {
                    const int seg = col >> 8, c = col & 255;
                    ushort* dst = seg == 0 ? O0 : (seg == 1 ? O1 : O2);
                    dst[row * 256 + c] = f2b(seg < 2 ? actf<1>(v) : v);
                }
            }
}

// ---------------- GEMM + LN + residual, BM=32, BN=256 full width ----------------
// out = resid + LN(A @ B)*g + b ; fp32 out + bf16 out.
__global__ __launch_bounds__(256) void gemm_ln32(
    const ushort* __restrict__ A, int lda,
    const ushort* __restrict__ Bt,
    const float* __restrict__ g, const float* __restrict__ bb,
    const float* __restrict__ rx0, const float* __restrict__ rx1,
    float* __restrict__ outf, ushort* __restrict__ outb, int K)
{
    __shared__ __align__(16) ushort As[32 * 32];
    __shared__ __align__(16) ushort Bs[256 * 32];
    __shared__ float red[2][4][32];
    const int t = threadIdx.x;
    const int wave = t >> 6, lane = t & 63;
    const int bm = blockIdx.x * 32;
    const int lr = lane & 15, kg = lane >> 4, lk = kg * 8;

    const int srow = t >> 2;
    const int sg = ((t & 3) * 8) ^ ((srow & 3) * 8);
    const ushort* aP = A + (size_t)(bm + srow) * lda + sg;
    const ushort* bP = Bt + (size_t)srow * K + sg;
    char* ldsA = (char*)As + wave * 1024;
    char* ldsB = (char*)Bs + wave * 1024;
    const size_t b64 = (size_t)64 * K;

    const f32x4 z4 = {0.f, 0.f, 0.f, 0.f};
    f32x4 acc[2][4];
    #pragma unroll
    for (int m = 0; m < 2; ++m)
        #pragma unroll
        for (int n = 0; n < 4; ++n) acc[m][n] = z4;

    for (int k0 = 0; k0 < K; k0 += 32) {
        if (srow < 32) gload16(aP + k0, ldsA);
        gload16(bP + k0, ldsB);
        gload16(bP + k0 + b64, ldsB + 4096);
        gload16(bP + k0 + 2 * b64, ldsB + 8192);
        gload16(bP + k0 + 3 * b64, ldsB + 12288);
        __syncthreads();

        short8v af[2], bfr[4];
        #pragma unroll
        for (int m = 0; m < 2; ++m) {
            const int r = m * 16 + lr;
            af[m] = *(const short8v*)&As[r * 32 + (lk ^ ((r & 3) * 8))];
        }
        #pragma unroll
        for (int n = 0; n < 4; ++n) {
            const int r = wave * 64 + n * 16 + lr;
            bfr[n] = *(const short8v*)&Bs[r * 32 + (lk ^ ((r & 3) * 8))];
        }
        #pragma unroll
        for (int m = 0; m < 2; ++m)
            #pragma unroll
            for (int n = 0; n < 4; ++n)
                acc[m][n] = __builtin_amdgcn_mfma_f32_16x16x32_bf16(af[m], bfr[n], acc[m][n], 0, 0, 0);
        __syncthreads();
    }

    #pragma unroll
    for (int m = 0; m < 2; ++m)
        #pragma unroll
        for (int j = 0; j < 4; ++j) {
            float s = 0.f, q = 0.f;
            #pragma unroll
            for (int n = 0; n < 4; ++n) { const float v = acc[m][n][j]; s += v; q += v * v; }
            #pragma unroll
            for (int mk = 1; mk < 16; mk <<= 1) { s += __shfl_xor(s, mk); q += __shfl_xor(q, mk); }
            if (lr == 0) {
                red[0][wave][m * 16 + kg * 4 + j] = s;
                red[1][wave][m * 16 + kg * 4 + j] = q;
            }
        }
    __syncthreads();

    float gv[4], bv[4];
    #pragma unroll
    for (int n = 0; n < 4; ++n) {
        const int col = wave * 64 + n * 16 + lr;
        gv[n] = g[col]; bv[n] = bb[col];
    }
    const float* rxb = (bm < RTOT) ? rx0 + (size_t)bm * CDIM : rx1 + (size_t)(bm - RTOT) * CDIM;

    #pragma unroll
    for (int m = 0; m < 2; ++m)
        #pragma unroll
        for (int j = 0; j < 4; ++j) {
            const int row = m * 16 + kg * 4 + j;
            const float tot = red[0][0][row] + red[0][1][row] + red[0][2][row] + red[0][3][row];
            const float tq  = red[1][0][row] + red[1][1][row] + red[1][2][row] + red[1][3][row];
            const float mu = tot * (1.0f / 256.0f);
            const float var = tq * (1.0f / 256.0f) - mu * mu;
            const float inv = rsqrtf(var + 1e-5f);
            const size_t go = (size_t)(bm + row) * CDIM;
            #pragma unroll
            for (int n = 0; n < 4; ++n) {
                const int col = wave * 64 + n * 16 + lr;
                float val = (acc[m][n][j] - mu) * inv * gv[n] + bv[n];
                val += rxb[(size_t)row * CDIM + col];
                outf[go + col] = val;
                outb[go + col] = f2b(val);
            }
        }
}

// ---------------- fused attention + Wm GEMM + LN1, BM=32 ----------------
// phase 1 (waves 0,1): msg[32][256] = (Q @ KV^T) * 1/(Q.Ksum+eps)  -> swizzled LDS tile
// phase 2 (all waves): mln = LN(msg @ Wm) * g1 + b1 -> bf16 out
__global__ __launch_bounds__(256) void attn_wm_ln(
    const ushort* __restrict__ Qb, const ushort* __restrict__ KVbT,
    const ushort* __restrict__ Ksb, const ushort* __restrict__ WmT,
    const float* __restrict__ g, const float* __restrict__ bb,
    ushort* __restrict__ mln, int xorv)
{
    __shared__ __align__(16) ushort Ms[32 * 256];
    __shared__ __align__(16) ushort Bs[256 * 32];
    __shared__ float red[2][4][32];
    const int t = threadIdx.x, wave = t >> 6, lane = t & 63;
    const int bm = blockIdx.x * 32;
    const int n = bm / SLEN, src = n ^ xorv;
    const int lr = lane & 15, kg = lane >> 4, lk = kg * 8;
    const f32x4 z4 = {0.f, 0.f, 0.f, 0.f};

    if (wave < 2) {
        const int rw = wave * 16;
        const size_t qrow = ((size_t)bm + rw + lr) * CDIM;
        char* mb = (char*)Ms;
        #pragma unroll
        for (int h = 0; h < NHEAD; ++h) {
            const short8v af = *(const short8v*)&Qb[qrow + h * 32 + kg * 8];
            const ushort* bbp = KVbT + ((size_t)(src * NHEAD + h)) * 1024;
            const short8v b0 = *(const short8v*)&bbp[lr * 32 + kg * 8];
            const short8v b1 = *(const short8v*)&bbp[(16 + lr) * 32 + kg * 8];
            const short8v bz = *(const short8v*)&Ksb[((size_t)(src * NHEAD + h)) * 512 + lr * 32 + kg * 8];
            f32x4 a0 = __builtin_amdgcn_mfma_f32_16x16x32_bf16(af, b0, z4, 0, 0, 0);
            f32x4 a1 = __builtin_amdgcn_mfma_f32_16x16x32_bf16(af, b1, z4, 0, 0, 0);
            f32x4 az = __builtin_amdgcn_mfma_f32_16x16x32_bf16(af, bz, z4, 0, 0, 0);
            #pragma unroll
            for (int j = 0; j < 4; ++j) {
                const float zj = __shfl(az[j], lane & 48);
                const float rz = 1.0f / (zj + 1e-6f);
                const int orow = rw + kg * 4 + j;
                const int swz = (orow & 7) << 4;
                *(ushort*)(mb + ((orow * 512 + (h * 32 + lr) * 2) ^ swz)) = f2b(a0[j] * rz);
                *(ushort*)(mb + ((orow * 512 + (h * 32 + 16 + lr) * 2) ^ swz)) = f2b(a1[j] * rz);
            }
        }
    }
    __syncthreads();

    const int srow = t >> 2;
    const int sg = ((t & 3) * 8) ^ ((srow & 3) * 8);
    const ushort* bP = WmT + (size_t)srow * 256 + sg;
    char* ldsB = (char*)Bs + wave * 1024;

    f32x4 acc[2][4];
    #pragma unroll
    for (int m = 0; m < 2; ++m)
        #pragma unroll
        for (int nn = 0; nn < 4; ++nn) acc[m][nn] = z4;

    for (int k0 = 0; k0 < 256; k0 += 32) {
        gload16(bP + k0, ldsB);
        gload16(bP + k0 + 64 * 256, ldsB + 4096);
        gload16(bP + k0 + 128 * 256, ldsB + 8192);
        gload16(bP + k0 + 192 * 256, ldsB + 12288);
        __syncthreads();

        short8v af[2], bfr[4];
        #pragma unroll
        for (int m = 0; m < 2; ++m) {
            const int r = m * 16 + lr;
            af[m] = *(const short8v*)((char*)Ms + ((r * 512 + k0 * 2 + kg * 16) ^ ((r & 7) << 4)));
        }
        #pragma unroll
        for (int nn = 0; nn < 4; ++nn) {
            const int r = wave * 64 + nn * 16 + lr;
            bfr[nn] = *(const short8v*)&Bs[r * 32 + (lk ^ ((r & 3) * 8))];
        }
        #pragma unroll
        for (int m = 0; m < 2; ++m)
            #pragma unroll
            for (int nn = 0; nn < 4; ++nn)
                acc[m][nn] = __builtin_amdgcn_mfma_f32_16x16x32_bf16(af[m], bfr[nn], acc[m][nn], 0, 0, 0);
        __syncthreads();
    }

    #pragma unroll
    for (int m = 0; m < 2; ++m)
        #pragma unroll
        for (int j = 0; j < 4; ++j) {
            float s = 0.f, q = 0.f;
            #pragma unroll
            for (int nn = 0; nn < 4; ++nn) { const float v = acc[m][nn][j]; s += v; q += v * v; }
            #pragma unroll
            for (int mk = 1; mk < 16; mk <<= 1) { s += __shfl_xor(s, mk); q += __shfl_xor(q, mk); }
            if (lr == 0) {
                red[0][wave][m * 16 + kg * 4 + j] = s;
                red[1][wave][m * 16 + kg * 4 + j] = q;
            }
        }
    __syncthreads();

    float gv[4], bv[4];
    #pragma unroll
    for (int nn = 0; nn < 4; ++nn) {
        const int col = wave * 64 + nn * 16 + lr;
        gv[nn] = g[col]; bv[nn] = bb[col];
    }
    #pragma unroll
    for (int m = 0; m < 2; ++m)
        #pragma unroll
        for (int j = 0; j < 4; ++j) {
            const int row = m * 16 + kg * 4 + j;
            const float tot = red[0][0][row] + red[0][1][row] + red[0][2][row] + red[0][3][row];
            const float tq  = red[1][0][row] + red[1][1][row] + red[1][2][row] + red[1][3][row];
            const float mu = tot * (1.0f / 256.0f);
            const float var = tq * (1.0f / 256.0f) - mu * mu;
            const float inv = rsqrtf(var + 1e-5f);
            const size_t go = (size_t)(bm + row) * CDIM;
            #pragma unroll
            for (int nn = 0; nn < 4; ++nn) {
                const int col = wave * 64 + nn * 16 + lr;
                mln[go + col] = f2b((acc[m][nn][j] - mu) * inv * gv[nn] + bv[nn]);
            }
        }
}

// ---------------- weight transpose + bf16: src [L][R][C] -> dst [L(dstride)][C][R] ----------------
__global__ __launch_bounds__(256) void wconv_t(
    const float* __restrict__ src, ushort* __restrict__ dst, int R, int C, size_t dstride)
{
    __shared__ float tile[32][33];
    const int l = blockIdx.z;
    const int r0 = blockIdx.y * 32, c0 = blockIdx.x * 32;
    const int tx = threadIdx.x & 31, ty = threadIdx.x >> 5;
    const float* s = src + (size_t)l * R * C;
    ushort* d = dst + (size_t)l * dstride;
    for (int i = ty; i < 32; i += 8) tile[i][tx] = s[(size_t)(r0 + i) * C + c0 + tx];
    __syncthreads();
    for (int i = ty; i < 32; i += 8) d[(size_t)(c0 + i) * R + r0 + tx] = f2b(tile[tx][i]);
}

// ---------------- KV partial reduction (bf16 in, fp32 partials) ----------------
__global__ __launch_bounds__(256) void kv_part_k(
    const ushort* __restrict__ Kb, const ushort* __restrict__ Vb,
    float* __restrict__ KVp, float* __restrict__ Ksp)
{
    const int blk = blockIdx.x;
    const int seg = blk % SEG;
    const int h = (blk / SEG) % NHEAD;
    const int n = blk / (SEG * NHEAD);          // 0..7
    const int s0 = seg * SCHUNK;
    __shared__ float Ks[16][32];
    __shared__ float Vs[16][32];
    const int t = threadIdx.x;
    const int rr = t >> 4, c2 = (t & 15) * 2;
    const int d = t >> 3, v0 = (t & 7) * 4;
    float a0 = 0, a1 = 0, a2 = 0, a3 = 0, ksum = 0;
    for (int c = 0; c < SCHUNK; c += 16) {
        const size_t off = ((size_t)(n * SLEN + s0 + c + rr)) * CDIM + h * HDIM + c2;
        const ushort2 ku = *(const ushort2*)&Kb[off];
        const ushort2 vu = *(const ushort2*)&Vb[off];
        Ks[rr][c2] = b2f(ku.x); Ks[rr][c2 + 1] = b2f(ku.y);
        Vs[rr][c2] = b2f(vu.x); Vs[rr][c2 + 1] = b2f(vu.y);
        __syncthreads();
        #pragma unroll
        for (int q = 0; q < 16; ++q) {
            const float kd = Ks[q][d];
            a0 += kd * Vs[q][v0 + 0];
            a1 += kd * Vs[q][v0 + 1];
            a2 += kd * Vs[q][v0 + 2];
            a3 += kd * Vs[q][v0 + 3];
        }
        if (t < 32) {
            #pragma unroll
            for (int q = 0; q < 16; ++q) ksum += Ks[q][t];
        }
        __syncthreads();
    }
    float* kvp = KVp + ((size_t)((n * NHEAD + h) * SEG + seg)) * 1024;
    kvp[t * 4 + 0] = a0;
    kvp[t * 4 + 1] = a1;
    kvp[t * 4 + 2] = a2;
    kvp[t * 4 + 3] = a3;
    if (t < 32) Ksp[((size_t)((n * NHEAD + h) * SEG + seg)) * 32 + t] = ksum;
}

// ---------------- KV reduce -> bf16 transposed KV + Ksum B-tiles ----------------
__global__ __launch_bounds__(256) void kv_reduce_k(
    const float* __restrict__ KVp, const float* __restrict__ Ksp,
    ushort* __restrict__ KVbT, ushort* __restrict__ Ksb)
{
    const int nh = blockIdx.x;      // 0..63
    const int t = threadIdx.x;
    #pragma unroll
    for (int i = 0; i < 4; ++i) {
        const int idx = t * 4 + i;
        const int v = idx >> 5, d = idx & 31;
        float s = 0;
        for (int seg = 0; seg < SEG; ++seg)
            s += KVp[((size_t)(nh * SEG + seg)) * 1024 + d * 32 + v];
        KVbT[(size_t)nh * 1024 + idx] = f2b(s);
    }
    #pragma unroll
    for (int i = 0; i < 2; ++i) {
        const int idx = t * 2 + i;
        const int c = idx >> 5, d = idx & 31;
        float s = 0;
        if (c == 0)
            for (int seg = 0; seg < SEG; ++seg)
                s += Ksp[((size_t)(nh * SEG + seg)) * 32 + d];
        Ksb[(size_t)nh * 512 + idx] = f2b(s);
    }
}

// ---------------- fp32 -> bf16 convert ----------------
__global__ __launch_bounds__(256) void cvt_in_k(const float* __restrict__ src, ushort* __restrict__ dst) {
    const size_t i = ((size_t)blockIdx.x * 256 + threadIdx.x) * 4;
    const float4 v = *(const float4*)&src[i];
    ushort4 ob = make_ushort4(f2b(v.x), f2b(v.y), f2b(v.z), f2b(v.w));
    *(ushort4*)&dst[i] = ob;
}

// ---------------- host-side orchestration ----------------
struct Ws {
    float *xf, *KVp, *Ksp;
    ushort *xb, *Qb, *Kb, *Vb, *h1b, *KVbT, *Ksb;
    ushort *WqkvT, *WmT, *W1T, *W2T;
};

static void layer_pass(const float* rx0, const float* rx1, float* destf, int xorv,
                       const ushort* WqkvT, const ushort* WmT,
                       const ushort* W1T, const ushort* W2T,
                       const float* g1, const float* b1,
                       const float* g2, const float* b2,
                       const Ws& w, hipStream_t stream)
{
    const dim3 blk(256);
    // 1. Q|K|V = split(xb @ [Wq|Wk|Wv]) over all 38400 rows
    gemm_bf16<0, false, 1><<<dim3(6, RALL / 128), blk, 0, stream>>>(
        w.xb, nullptr, 256, WqkvT, w.Qb, w.Kb, w.Vb, 768, 256);
    // 2-3. per-batch KV aggregate (pre-layer state both halves -> cross-safe)
    kv_part_k<<<dim3(NB * NHEAD * SEG), blk, 0, stream>>>(w.Kb, w.Vb, w.KVp, w.Ksp);
    kv_reduce_k<<<dim3(NB * NHEAD), blk, 0, stream>>>(w.KVp, w.Ksp, w.KVbT, w.Ksb);
    // 4. mln = LN(attn_msg @ Wm) -> Kb (raw K dead)
    attn_wm_ln<<<dim3(RALL / 32), blk, 0, stream>>>(
        w.Qb, w.KVbT, w.Ksb, WmT, g1, b1, w.Kb, xorv);
    // 5. h1 = relu(concat(xb, mln) @ W1)
    gemm_bf16<2, true, 0><<<dim3(4, RALL / 128), blk, 0, stream>>>(
        w.xb, w.Kb, 256, W1T, w.h1b, nullptr, nullptr, 512, 512);
    // 6. x' = resid + LN(h1 @ W2) -> destf (fp32) + xb (bf16, in place)
    gemm_ln32<<<dim3(RALL / 32), blk, 0, stream>>>(
        w.h1b, 512, W2T, g2, b2, rx0, rx1, destf, w.xb, 512);
}

extern "C" void kernel_launch(void* const* d_in, const int* in_sizes, int n_in,
                              void* d_out, int out_size, void* d_ws, size_t ws_size,
                              hipStream_t stream) {
    (void)in_sizes; (void)n_in; (void)out_size; (void)ws_size;
    const float* f0in = (const float*)d_in[0];
    const float* f1in = (const float*)d_in[1];
    const float* WqA = (const float*)d_in[2];
    const float* WkA = (const float*)d_in[3];
    const float* WvA = (const float*)d_in[4];
    const float* WmA = (const float*)d_in[5];
    const float* W1A = (const float*)d_in[6];
    const float* W2A = (const float*)d_in[7];
    const float* g1A = (const float*)d_in[8];
    const float* b1A = (const float*)d_in[9];
    const float* g2A = (const float*)d_in[10];
    const float* b2A = (const float*)d_in[11];

    float* outf = (float*)d_out;                 // [RALL][256] = out0 | out1
    const size_t RC = (size_t)RTOT * CDIM;
    const size_t RAC = (size_t)RALL * CDIM;

    float* wsf = (float*)d_ws;
    Ws w;
    w.xf  = wsf;                                  // RAC fp32
    w.KVp = w.xf + RAC;                           // 64*SEG*1024 fp32
    w.Ksp = w.KVp + (size_t)64 * SEG * 1024;      // 64*SEG*32 fp32
    ushort* p = (ushort*)(w.Ksp + 64 * SEG * 32);
    w.xb = p;   p += RAC;
    w.Qb = p;   p += RAC;
    w.Kb = p;   p += RAC;
    w.Vb = p;   p += RAC;
    w.h1b = p;  p += (size_t)RALL * 512;
    w.KVbT = p; p += 64 * 1024;
    w.Ksb = p;  p += 64 * 512;
    w.WqkvT = p; p += (size_t)8 * 768 * 256;
    w.WmT = p;  p += (size_t)8 * 256 * 256;
    w.W1T = p;  p += (size_t)8 * 512 * 512;
    w.W2T = p;  p += (size_t)8 * 512 * 256;

    const dim3 blk(256);
    wconv_t<<<dim3(8, 8, 8), blk, 0, stream>>>(WqA, w.WqkvT,             256, 256, 768 * 256);
    wconv_t<<<dim3(8, 8, 8), blk, 0, stream>>>(WkA, w.WqkvT + 256 * 256, 256, 256, 768 * 256);
    wconv_t<<<dim3(8, 8, 8), blk, 0, stream>>>(WvA, w.WqkvT + 512 * 256, 256, 256, 768 * 256);
    wconv_t<<<dim3(8, 8, 8), blk, 0, stream>>>(WmA, w.WmT, 256, 256, 65536);
    wconv_t<<<dim3(16, 16, 8), blk, 0, stream>>>(W1A, w.W1T, 512, 512, 262144);
    wconv_t<<<dim3(8, 16, 8), blk, 0, stream>>>(W2A, w.W2T, 512, 256, 131072);

    cvt_in_k<<<dim3(RC / 1024), blk, 0, stream>>>(f0in, w.xb);
    cvt_in_k<<<dim3(RC / 1024), blk, 0, stream>>>(f1in, w.xb + RC);

    for (int l = 0; l < 8; ++l) {
        const int xorv = (l & 1) ? 4 : 0;                 // cross layers swap KV source
        const float* rx0 = (l == 0) ? f0in : w.xf;
        const float* rx1 = (l == 0) ? f1in : w.xf + RC;
        float* destf = (l == 7) ? outf : w.xf;
        layer_pass(rx0, rx1, destf, xorv,
                   w.WqkvT + (size_t)l * 768 * 256,
                   w.WmT + (size_t)l * 65536,
                   w.W1T + (size_t)l * 262144,
                   w.W2T + (size_t)l * 131072,
                   g1A + l * 256, b1A + l * 256, g2A + l * 256, b2A + l * 256,
                   w, stream);
    }
}